// Round 17
// baseline (980.351 us; speedup 1.0000x reference)
//
#include <hip/hip_runtime.h>
#include <math.h>

#define NHh   16
#define QL    1024
#define KL    2048
#define SCALEh 0.125f

typedef __attribute__((ext_vector_type(8))) short s8v;
typedef __attribute__((ext_vector_type(4))) float f4v;

#define MFMA16(a,b,c) __builtin_amdgcn_mfma_f32_16x16x32_bf16((a),(b),(c),0,0,0)

__device__ __forceinline__ short f2bf(float x) {
  unsigned u = __float_as_uint(x);
  return (short)((u + 0x7fffu + ((u >> 16) & 1u)) >> 16);
}
__device__ __forceinline__ float bf2f(short s) {
  return __uint_as_float(((unsigned)(unsigned short)s) << 16);
}

// ---------------------------------------------------------------------------
// split-bf16 MFMA GEMM: C[m][n] = sum_k A[m][k]*Bmat[n][k], K=1024, tile 128x128
// MODE0: A=[mems;w] (M=4096), N=3072; epilogue: Qw/Qr hi/lo (+bias), K hi/lo, V^T bf16
// MODE1: A=r (M=2048), N=1024; epilogue: RK hi/lo [head][row][d]
// MODE2: A=(avp0+avp1)*linv_row; epilogue: out fp32
// LDS XOR swizzle: slot = row*8 + (kgroup ^ (row&7))
// ---------------------------------------------------------------------------
template<int MODE>
__global__ __launch_bounds__(256)
void gemm_mfma(const float* __restrict__ A0, const float* __restrict__ A1,
               const float* __restrict__ Bmat,
               short* __restrict__ P0h, short* __restrict__ P0l,
               short* __restrict__ P1h, short* __restrict__ P1l,
               short* __restrict__ P2h, short* __restrict__ P2l,
               short* __restrict__ P3,
               float* __restrict__ Ofp,
               const float* __restrict__ rwb, const float* __restrict__ rrb,
               const float* __restrict__ Wl)
{
  __shared__ short Ah[128*64];
  __shared__ short Al[128*64];
  __shared__ short Bh[128*64];
  __shared__ short Bl[128*64];
  const int n0 = blockIdx.x * 128, m0 = blockIdx.y * 128;
  if (MODE == 0 && n0 < 1024 && m0 < 2048) return;   // q rows t<1024 are discarded
  const int tid = threadIdx.x;
  const int L = tid & 63, lr = L & 15, lg = L >> 4;
  const int wid = tid >> 6, wm = wid >> 1, wn = wid & 1;
  const int srow = tid >> 1, sseg = tid & 1;

  const float* arow;
  const float* arow2 = nullptr;
  if (MODE == 0) {
    int m = m0 + srow;
    arow = (m < 2048) ? (A0 + (size_t)m * 1024) : (A1 + (size_t)(m - 2048) * 1024);
  } else {
    arow = A0 + (size_t)(m0 + srow) * 1024;
    if (MODE == 2) arow2 = A1 + (size_t)(m0 + srow) * 1024;
  }
  const float* brow = Bmat + (size_t)(n0 + srow) * 1024;

  const f4v fz = {0.f, 0.f, 0.f, 0.f};
  f4v acc[4][4];
#pragma unroll
  for (int a = 0; a < 4; ++a)
#pragma unroll
    for (int bq = 0; bq < 4; ++bq) acc[a][bq] = fz;

  for (int k0 = 0; k0 < 1024; k0 += 64) {
    __syncthreads();
    {
      float wgt = 1.0f;
      if (MODE == 2) {
        int m = m0 + srow;
        wgt = Wl[((size_t)((m & 1) * NHh) + (k0 >> 6)) * 1024 + (m >> 1)];
      }
      const float* pa = arow + k0 + sseg * 32;
#pragma unroll
      for (int v = 0; v < 4; ++v) {
        float4 f0 = *reinterpret_cast<const float4*>(pa + v * 8);
        float4 f1 = *reinterpret_cast<const float4*>(pa + v * 8 + 4);
        if (MODE == 2) {
          const float* pa2 = arow2 + k0 + sseg * 32;
          float4 g0 = *reinterpret_cast<const float4*>(pa2 + v * 8);
          float4 g1 = *reinterpret_cast<const float4*>(pa2 + v * 8 + 4);
          f0.x = (f0.x + g0.x) * wgt; f0.y = (f0.y + g0.y) * wgt;
          f0.z = (f0.z + g0.z) * wgt; f0.w = (f0.w + g0.w) * wgt;
          f1.x = (f1.x + g1.x) * wgt; f1.y = (f1.y + g1.y) * wgt;
          f1.z = (f1.z + g1.z) * wgt; f1.w = (f1.w + g1.w) * wgt;
        }
        float bf[8] = {f0.x, f0.y, f0.z, f0.w, f1.x, f1.y, f1.z, f1.w};
        s8v hi, lo;
#pragma unroll
        for (int e = 0; e < 8; ++e) {
          short h = f2bf(bf[e]); hi[e] = h; lo[e] = f2bf(bf[e] - bf2f(h));
        }
        int slot = srow * 8 + ((sseg * 4 + v) ^ (srow & 7));
        *reinterpret_cast<s8v*>(Ah + slot * 8) = hi;
        *reinterpret_cast<s8v*>(Al + slot * 8) = lo;
      }
      const float* pb = brow + k0 + sseg * 32;
#pragma unroll
      for (int v = 0; v < 4; ++v) {
        float4 f0 = *reinterpret_cast<const float4*>(pb + v * 8);
        float4 f1 = *reinterpret_cast<const float4*>(pb + v * 8 + 4);
        float bf[8] = {f0.x, f0.y, f0.z, f0.w, f1.x, f1.y, f1.z, f1.w};
        s8v hi, lo;
#pragma unroll
        for (int e = 0; e < 8; ++e) {
          short h = f2bf(bf[e]); hi[e] = h; lo[e] = f2bf(bf[e] - bf2f(h));
        }
        int slot = srow * 8 + ((sseg * 4 + v) ^ (srow & 7));
        *reinterpret_cast<s8v*>(Bh + slot * 8) = hi;
        *reinterpret_cast<s8v*>(Bl + slot * 8) = lo;
      }
    }
    __syncthreads();
#pragma unroll
    for (int ks = 0; ks < 2; ++ks) {
      s8v a_h[4], a_l[4], b_h[4], b_l[4];
#pragma unroll
      for (int x = 0; x < 4; ++x) {
        int ra = wm * 64 + x * 16 + lr;
        int sa = ra * 8 + ((ks * 4 + lg) ^ (ra & 7));
        a_h[x] = *reinterpret_cast<const s8v*>(Ah + sa * 8);
        a_l[x] = *reinterpret_cast<const s8v*>(Al + sa * 8);
        int rb = wn * 64 + x * 16 + lr;
        int sb = rb * 8 + ((ks * 4 + lg) ^ (rb & 7));
        b_h[x] = *reinterpret_cast<const s8v*>(Bh + sb * 8);
        b_l[x] = *reinterpret_cast<const s8v*>(Bl + sb * 8);
      }
#pragma unroll
      for (int mf = 0; mf < 4; ++mf)
#pragma unroll
        for (int nf = 0; nf < 4; ++nf) {
          acc[mf][nf] = MFMA16(a_l[mf], b_h[nf], acc[mf][nf]);
          acc[mf][nf] = MFMA16(a_h[mf], b_l[nf], acc[mf][nf]);
          acc[mf][nf] = MFMA16(a_h[mf], b_h[nf], acc[mf][nf]);
        }
    }
  }
  // ---- epilogue: C/D layout col=lane&15, row=(lane>>4)*4+reg (m89-verified)
  const int sec = (MODE == 0) ? (n0 >> 10) : 0;
#pragma unroll
  for (int mf = 0; mf < 4; ++mf)
#pragma unroll
    for (int nf = 0; nf < 4; ++nf) {
      const int n = n0 + wn * 64 + nf * 16 + lr;
#pragma unroll
      for (int r = 0; r < 4; ++r) {
        const int m = m0 + wm * 64 + mf * 16 + lg * 4 + r;
        float val = acc[mf][nf][r];
        if (MODE == 2) {
          Ofp[(size_t)m * 1024 + n] = val;
        } else if (MODE == 1) {
          int nn = n >> 6, d = n & 63;
          size_t idx = (((size_t)nn * KL + m) << 6) + d;
          short h = f2bf(val);
          P0h[idx] = h; P0l[idx] = f2bf(val - bf2f(h));
        } else {
          int b = m & 1, t = m >> 1;
          if (sec == 0) {                       // q section: t >= 1024 guaranteed
            int i = t - 1024;
            int nn = n >> 6, d = n & 63;
            size_t idx = (((size_t)(b * NHh + nn) * QL + i) << 6) + d;
            float qw = val + rwb[n];
            float qr = val + rrb[n];
            short h = f2bf(qw);
            P0h[idx] = h; P0l[idx] = f2bf(qw - bf2f(h));
            h = f2bf(qr);
            P1h[idx] = h; P1l[idx] = f2bf(qr - bf2f(h));
          } else if (sec == 1) {                // K
            int c = n - 1024; int nn = c >> 6, d = c & 63;
            size_t idx = (((size_t)(b * NHh + nn) * KL + t) << 6) + d;
            short h = f2bf(val);
            P2h[idx] = h; P2l[idx] = f2bf(val - bf2f(h));
          } else {                              // V^T single bf16 [bn][d][t]
            int c = n - 2048; int nn = c >> 6, d = c & 63;
            size_t idx = ((size_t)(b * NHh + nn) * 64 + d) * KL + t;
            P3[idx] = f2bf(val);
          }
        }
      }
    }
}

// ---------------------------------------------------------------------------
// Fused attention — r14's proven 226-us shape (1 wave / 32 q-rows per block,
// inline just-in-time loads, setprio, r3-refchecked rel-shift algebra, XCD
// decode). Round-17 deltas: (1) qw fragments are RELOADED per tile per mf
// (same cache line all kernel -> L1 hits) instead of held in 32 registers,
// and launch_bounds(64,4) caps VGPR at 128 -> 4 waves/SIMD instead of 3
// (r14: VGPR=160 -> 3/SIMD; waves measured ~25% duty, stall-bound, so +33%
// residency should convert ~1:1). (2) No l tracking — rescale_prob now
// computes row sums itself; attn writes only p' and avp partials.
// Grid 2048 flat: xcd=orig&7 -> bn, iblk (32x32 rows), ch (2 j-chunks).
// BD rel-shift: G[ir][c] = Qr_i * RK[BASE+c], BASE = 992-i0+j0; mf0 uses
// c in [16,95] (skip ci0), mf1 uses c in [0,79] (skip ci5);
// gather cl = 31 - mf*16 - ir16 + jf*16 + lr.
// ---------------------------------------------------------------------------
__global__ __launch_bounds__(64, 4)
void attn_fused(const short* __restrict__ Qwh, const short* __restrict__ Qwl,
                const short* __restrict__ Qrh, const short* __restrict__ Qrl,
                const short* __restrict__ Kh,  const short* __restrict__ Klo,
                const short* __restrict__ RKh, const short* __restrict__ RKl,
                const short* __restrict__ Vb,
                float* __restrict__ prob,
                float* __restrict__ avp)
{
  __shared__ float Gs[96 * 20];     // [c][i16] fp32, per-mf sequential reuse
  __shared__ short Ps[32 * 72];     // P tile bf16 for PV A-frags
  const int L = threadIdx.x;
  const int lr = L & 15, lg = L >> 4;
  // XCD-locality decode (bijection over 2048 = 8 xcd x 4 bnl x 64 rest)
  const int orig = blockIdx.x;
  const int xcd  = orig & 7;
  const int k2   = orig >> 3;              // 0..255
  const int bn   = xcd * 4 + (k2 >> 6);    // 0..31
  const int rest = k2 & 63;
  const int iblk = rest >> 1, ch = rest & 1;
  const int nh = bn & 15, b = bn >> 4;
  const int i0 = iblk * 32;
  const f4v fz = {0.f, 0.f, 0.f, 0.f};

  int T = ((i0 + 1055) >> 6) + 1; if (T > 32) T = 32;
  const int t0 = (ch * T) >> 1;
  const int t1 = ((ch + 1) * T) >> 1;

  // Qr frags held in registers (used in BD); Qw reloaded per tile (L1-hot)
  s8v qr_h[2][2], qr_l[2][2];
#pragma unroll
  for (int mf = 0; mf < 2; ++mf)
#pragma unroll
    for (int ks = 0; ks < 2; ++ks) {
      size_t idx = (((size_t)bn * QL + i0 + mf * 16 + lr) << 6) + ks * 32 + lg * 8;
      qr_h[mf][ks] = *reinterpret_cast<const s8v*>(Qrh + idx);
      qr_l[mf][ks] = *reinterpret_cast<const s8v*>(Qrl + idx);
    }

  f4v av[2][4];
#pragma unroll
  for (int mf = 0; mf < 2; ++mf)
#pragma unroll
    for (int r = 0; r < 4; ++r) av[mf][r] = fz;

  float* probb = prob + (size_t)bn * QL * KL;

  for (int jt = t0; jt < t1; ++jt) {
    const int j0 = jt * 64;
    const int BASE = 992 - i0 + j0;
    // ---- BD window GEMM (inline loads, shared across both mf)
    f4v gacc[2][5];
#pragma unroll
    for (int mf = 0; mf < 2; ++mf)
#pragma unroll
      for (int gi = 0; gi < 5; ++gi) gacc[mf][gi] = fz;
    __builtin_amdgcn_s_setprio(1);
#pragma unroll
    for (int ci = 0; ci < 6; ++ci) {
      int rg = BASE + ci * 16 + lr;
      rg = rg < 0 ? 0 : (rg > 2047 ? 2047 : rg);  // clamped rows feed masked elems only
      size_t ridx = ((size_t)nh * KL + rg) << 6;
      s8v r_h[2], r_l[2];
#pragma unroll
      for (int ks = 0; ks < 2; ++ks) {
        r_h[ks] = *reinterpret_cast<const s8v*>(RKh + ridx + ks * 32 + lg * 8);
        r_l[ks] = *reinterpret_cast<const s8v*>(RKl + ridx + ks * 32 + lg * 8);
      }
#pragma unroll
      for (int mf = 0; mf < 2; ++mf) {
        if (mf == 0 && ci == 0) continue;   // mf0 uses c in [16,95]
        if (mf == 1 && ci == 5) continue;   // mf1 uses c in [0,79]
        const int gi = (mf == 0) ? (ci - 1) : ci;
#pragma unroll
        for (int ks = 0; ks < 2; ++ks) {
          gacc[mf][gi] = MFMA16(qr_l[mf][ks], r_h[ks], gacc[mf][gi]);
          gacc[mf][gi] = MFMA16(qr_h[mf][ks], r_l[ks], gacc[mf][gi]);
          gacc[mf][gi] = MFMA16(qr_h[mf][ks], r_h[ks], gacc[mf][gi]);
        }
      }
    }
    __builtin_amdgcn_s_setprio(0);
    // ---- per mf: spill G, AC GEMM (inline K + reloaded Qw), gather+exp+write
#pragma unroll
    for (int mf = 0; mf < 2; ++mf) {
#pragma unroll
      for (int gi = 0; gi < 5; ++gi) {
        int c = (mf == 0 ? 16 : 0) + gi * 16 + lr;
        *reinterpret_cast<f4v*>(Gs + c * 20 + lg * 4) = gacc[mf][gi];
      }
      s8v qwh[2], qwl[2];
      {
        size_t qidx = (((size_t)bn * QL + i0 + mf * 16 + lr) << 6);
#pragma unroll
        for (int ks = 0; ks < 2; ++ks) {
          qwh[ks] = *reinterpret_cast<const s8v*>(Qwh + qidx + ks * 32 + lg * 8);
          qwl[ks] = *reinterpret_cast<const s8v*>(Qwl + qidx + ks * 32 + lg * 8);
        }
      }
      f4v sfr[4];
      __builtin_amdgcn_s_setprio(1);
#pragma unroll
      for (int jf = 0; jf < 4; ++jf) {
        sfr[jf] = fz;
        size_t kidx = ((size_t)bn * KL + j0 + jf * 16 + lr) << 6;
#pragma unroll
        for (int ks = 0; ks < 2; ++ks) {
          s8v k_h = *reinterpret_cast<const s8v*>(Kh  + kidx + ks * 32 + lg * 8);
          s8v k_l = *reinterpret_cast<const s8v*>(Klo + kidx + ks * 32 + lg * 8);
          sfr[jf] = MFMA16(qwl[ks], k_h, sfr[jf]);
          sfr[jf] = MFMA16(qwh[ks], k_l, sfr[jf]);
          sfr[jf] = MFMA16(qwh[ks], k_h, sfr[jf]);
        }
      }
      __builtin_amdgcn_s_setprio(0);
#pragma unroll
      for (int jf = 0; jf < 4; ++jf) {
#pragma unroll
        for (int r = 0; r < 4; ++r) {
          const int ir16 = lg * 4 + r;
          const int i = i0 + mf * 16 + ir16;
          const int j = j0 + jf * 16 + lr;
          const int cl = 31 - mf * 16 - ir16 + jf * 16 + lr;
          float s = (sfr[jf][r] + Gs[cl * 20 + ir16]) * SCALEh;
          float p = (j <= i + 1024) ? __expf(s) : 0.f;
          probb[(size_t)i * KL + j] = p;
          Ps[(mf * 16 + ir16) * 72 + jf * 16 + lr] = f2bf(p);
        }
      }
    }
    // ---- PV: inline V loads shared across both mf
    __builtin_amdgcn_s_setprio(1);
#pragma unroll
    for (int ks = 0; ks < 2; ++ks) {
      s8v pa[2];
#pragma unroll
      for (int mf = 0; mf < 2; ++mf)
        pa[mf] = *reinterpret_cast<const s8v*>(Ps + (mf * 16 + lr) * 72 + ks * 32 + lg * 8);
#pragma unroll
      for (int df = 0; df < 4; ++df) {
        s8v vfr = *reinterpret_cast<const s8v*>(
            Vb + ((size_t)bn * 64 + df * 16 + lr) * KL + j0 + ks * 32 + lg * 8);
#pragma unroll
        for (int mf = 0; mf < 2; ++mf)
          av[mf][df] = MFMA16(pa[mf], vfr, av[mf][df]);
      }
    }
    __builtin_amdgcn_s_setprio(0);
  }

  // ---- AV' partials
#pragma unroll
  for (int mf = 0; mf < 2; ++mf)
#pragma unroll
    for (int df = 0; df < 4; ++df)
#pragma unroll
      for (int r = 0; r < 4; ++r) {
        int i = i0 + mf * 16 + lg * 4 + r;
        int d = df * 16 + lr;
        avp[(size_t)ch * 2097152 + ((size_t)i * 2 + b) * 1024 + nh * 64 + d] = av[mf][df][r];
      }
}

// ---------------------------------------------------------------------------
// prob[row][j] = p'[row][j] / l_row for valid j (else exact 0), where
// l_row = sum_j p'. Computes the row sum itself (the row must be read anyway),
// skips reading fully-masked chunks, and writes linv for the W_o GEMM.
// ---------------------------------------------------------------------------
__global__ __launch_bounds__(256)
void rescale_prob(float* __restrict__ prob, float* __restrict__ linv)
{
  __shared__ float red[8];
  const int row = blockIdx.x;                 // bn*1024 + i
  const int i = row & 1023;
  const int lim = i + 1024;                   // j <= lim valid
  const int tid = threadIdx.x;
  const int jb = tid * 8;
  float* p = prob + ((size_t)row << 11) + jb;

  float4 a = {0.f, 0.f, 0.f, 0.f}, c = {0.f, 0.f, 0.f, 0.f};
  if (jb <= lim) {                            // at least one valid element
    a = *reinterpret_cast<const float4*>(p);
    c = *reinterpret_cast<const float4*>(p + 4);
    if (jb + 1 > lim) a.y = 0.f;
    if (jb + 2 > lim) a.z = 0.f;
    if (jb + 3 > lim) a.w = 0.f;
    if (jb + 4 > lim) c.x = 0.f;
    if (jb + 5 > lim) c.y = 0.f;
    if (jb + 6 > lim) c.z = 0.f;
    if (jb + 7 > lim) c.w = 0.f;
  }
  float sum = a.x + a.y + a.z + a.w + c.x + c.y + c.z + c.w;
#pragma unroll
  for (int mk = 1; mk <= 32; mk <<= 1) sum += __shfl_xor(sum, mk, 64);
  if ((tid & 63) == 0) red[tid >> 6] = sum;
  __syncthreads();
  float l = red[0] + red[1] + red[2] + red[3];
  float wgt = 1.0f / l;
  if (tid == 0) linv[row] = wgt;

  a.x *= wgt; a.y *= wgt; a.z *= wgt; a.w *= wgt;
  c.x *= wgt; c.y *= wgt; c.z *= wgt; c.w *= wgt;
  *reinterpret_cast<float4*>(p) = a;
  *reinterpret_cast<float4*>(p + 4) = c;
}

// ---------------------------------------------------------------------------
extern "C" void kernel_launch(void* const* d_in, const int* in_sizes, int n_in,
                              void* d_out, int out_size, void* d_ws, size_t ws_size,
                              hipStream_t stream)
{
  (void)in_sizes; (void)n_in; (void)out_size; (void)ws_size;
  const float* w    = (const float*)d_in[0];
  const float* r    = (const float*)d_in[1];
  const float* rwb  = (const float*)d_in[2];
  const float* rrb  = (const float*)d_in[3];
  const float* mems = (const float*)d_in[4];
  const float* Wqkv = (const float*)d_in[5];
  const float* Wr   = (const float*)d_in[6];
  const float* Wo   = (const float*)d_in[7];

  float* out  = (float*)d_out;
  float* prob = out + 2097152;

  // workspace: 67,371,008 B total (identical to the round-1/14 passing layout)
  short* Qwh = (short*)d_ws;
  short* Qwl = Qwh + 2097152;
  short* Qrh = Qwl + 2097152;
  short* Qrl = Qrh + 2097152;
  short* Kh  = Qrl + 2097152;
  short* Klo = Kh  + 4194304;
  short* Vb  = Klo + 4194304;
  short* RKh = Vb  + 4194304;
  short* RKl = RKh + 2097152;
  float* avp  = (float*)(RKl + 2097152);    // 2 x 2,097,152 floats
  float* linv = avp + 4194304;              // 32,768 floats

  gemm_mfma<0><<<dim3(24, 32), 256, 0, stream>>>(
      mems, w, Wqkv, Qwh, Qwl, Qrh, Qrl, Kh, Klo, Vb, nullptr, rwb, rrb, nullptr);
  gemm_mfma<1><<<dim3(8, 16), 256, 0, stream>>>(
      r, nullptr, Wr, RKh, RKl, nullptr, nullptr, nullptr, nullptr, nullptr,
      nullptr, nullptr, nullptr, nullptr);
  attn_fused<<<dim3(2048), 64, 0, stream>>>(
      Qwh, Qwl, Qrh, Qrl, Kh, Klo, RKh, RKl, Vb, prob, avp);
  rescale_prob<<<32768, 256, 0, stream>>>(prob, linv);
  gemm_mfma<2><<<dim3(8, 16), 256, 0, stream>>>(
      avp, avp + 2097152, Wo, nullptr, nullptr, nullptr, nullptr, nullptr, nullptr,
      nullptr, out, nullptr, nullptr, linv);
}

// Round 18
// 550.438 us; speedup vs baseline: 1.7810x; 1.7810x over previous
//
#include <hip/hip_runtime.h>
#include <math.h>

#define NHh   16
#define QL    1024
#define KL    2048
#define SCALEh 0.125f

typedef __attribute__((ext_vector_type(8))) short s8v;
typedef __attribute__((ext_vector_type(4))) short s4v;
typedef __attribute__((ext_vector_type(4))) float f4v;

#define MFMA16(a,b,c) __builtin_amdgcn_mfma_f32_16x16x32_bf16((a),(b),(c),0,0,0)

__device__ __forceinline__ short f2bf(float x) {
  unsigned u = __float_as_uint(x);
  return (short)((u + 0x7fffu + ((u >> 16) & 1u)) >> 16);
}
__device__ __forceinline__ float bf2f(short s) {
  return __uint_as_float(((unsigned)(unsigned short)s) << 16);
}

// ---------------------------------------------------------------------------
// One-shot fp32 -> split-bf16 (hi/lo) conversion of gemm0 operands.
// Row r < 4096: A = [mems;w] row; else B = Wqkv row (r-4096). One row/block.
// Removes the ~14 VALU ops/elem conversion from gemm0's k-loop (done 24x per
// A tile there); here each element is converted exactly once (~10 us total).
// ---------------------------------------------------------------------------
__global__ __launch_bounds__(256)
void convert_k(const float* __restrict__ mems, const float* __restrict__ w,
               const float* __restrict__ Wqkv,
               short* __restrict__ Ah, short* __restrict__ Al,
               short* __restrict__ Bh, short* __restrict__ Bl)
{
  const int row = blockIdx.x;
  const int t = threadIdx.x;            // 256 threads x 4 elems = 1024
  const float* src;
  short *dh, *dl;
  size_t r2;
  if (row < 4096) {
    src = (row < 2048) ? (mems + (size_t)row * 1024)
                       : (w + (size_t)(row - 2048) * 1024);
    dh = Ah; dl = Al; r2 = row;
  } else {
    src = Wqkv + (size_t)(row - 4096) * 1024;
    dh = Bh; dl = Bl; r2 = row - 4096;
  }
  float4 v = *reinterpret_cast<const float4*>(src + t * 4);
  short h0 = f2bf(v.x), h1 = f2bf(v.y), h2 = f2bf(v.z), h3 = f2bf(v.w);
  s4v hi = {h0, h1, h2, h3};
  s4v lo = {f2bf(v.x - bf2f(h0)), f2bf(v.y - bf2f(h1)),
            f2bf(v.z - bf2f(h2)), f2bf(v.w - bf2f(h3))};
  *reinterpret_cast<s4v*>(dh + r2 * 1024 + t * 4) = hi;
  *reinterpret_cast<s4v*>(dl + r2 * 1024 + t * 4) = lo;
}

// ---------------------------------------------------------------------------
// split-bf16 MFMA GEMM: C[m][n] = sum_k A[m][k]*Bmat[n][k], K=1024, tile 128x128
// MODE0: A/B pre-converted bf16 hi/lo (SA*/SB*) — staging is pure 16B loads,
//        zero conversion VALU; epilogue: Qw/Qr hi/lo (+bias), K hi/lo, V^T bf16
// MODE1: A=r fp32 (inline convert); epilogue: RK hi/lo [head][row][d]
// MODE2: A=(avp0+avp1)*linv_row fp32; epilogue: out fp32
// LDS XOR swizzle: slot = row*8 + (kgroup ^ (row&7))
// ---------------------------------------------------------------------------
template<int MODE>
__global__ __launch_bounds__(256)
void gemm_mfma(const float* __restrict__ A0, const float* __restrict__ A1,
               const float* __restrict__ Bmat,
               const short* __restrict__ SAh, const short* __restrict__ SAl,
               const short* __restrict__ SBh, const short* __restrict__ SBl,
               short* __restrict__ P0h, short* __restrict__ P0l,
               short* __restrict__ P1h, short* __restrict__ P1l,
               short* __restrict__ P2h, short* __restrict__ P2l,
               short* __restrict__ P3,
               float* __restrict__ Ofp,
               const float* __restrict__ rwb, const float* __restrict__ rrb,
               const float* __restrict__ Wl)
{
  __shared__ short Ah[128*64];
  __shared__ short Al[128*64];
  __shared__ short Bh[128*64];
  __shared__ short Bl[128*64];
  const int n0 = blockIdx.x * 128, m0 = blockIdx.y * 128;
  if (MODE == 0 && n0 < 1024 && m0 < 2048) return;   // q rows t<1024 are discarded
  const int tid = threadIdx.x;
  const int L = tid & 63, lr = L & 15, lg = L >> 4;
  const int wid = tid >> 6, wm = wid >> 1, wn = wid & 1;
  const int srow = tid >> 1, sseg = tid & 1;

  const float* arow = nullptr;
  const float* arow2 = nullptr;
  const short *sa_h, *sa_l, *sb_h, *sb_l;
  if (MODE == 0) {
    sa_h = SAh + (size_t)(m0 + srow) * 1024;
    sa_l = SAl + (size_t)(m0 + srow) * 1024;
    sb_h = SBh + (size_t)(n0 + srow) * 1024;
    sb_l = SBl + (size_t)(n0 + srow) * 1024;
  } else {
    arow = A0 + (size_t)(m0 + srow) * 1024;
    if (MODE == 2) arow2 = A1 + (size_t)(m0 + srow) * 1024;
  }
  const float* brow = (MODE == 0) ? nullptr : (Bmat + (size_t)(n0 + srow) * 1024);

  const f4v fz = {0.f, 0.f, 0.f, 0.f};
  f4v acc[4][4];
#pragma unroll
  for (int a = 0; a < 4; ++a)
#pragma unroll
    for (int bq = 0; bq < 4; ++bq) acc[a][bq] = fz;

  for (int k0 = 0; k0 < 1024; k0 += 64) {
    __syncthreads();
    if (MODE == 0) {
#pragma unroll
      for (int v = 0; v < 4; ++v) {
        int off = k0 + sseg * 32 + v * 8;
        int slot = srow * 8 + ((sseg * 4 + v) ^ (srow & 7));
        *reinterpret_cast<s8v*>(Ah + slot * 8) = *reinterpret_cast<const s8v*>(sa_h + off);
        *reinterpret_cast<s8v*>(Al + slot * 8) = *reinterpret_cast<const s8v*>(sa_l + off);
        *reinterpret_cast<s8v*>(Bh + slot * 8) = *reinterpret_cast<const s8v*>(sb_h + off);
        *reinterpret_cast<s8v*>(Bl + slot * 8) = *reinterpret_cast<const s8v*>(sb_l + off);
      }
    } else {
      float wgt = 1.0f;
      if (MODE == 2) {
        int m = m0 + srow;
        wgt = Wl[((size_t)((m & 1) * NHh) + (k0 >> 6)) * 1024 + (m >> 1)];
      }
      const float* pa = arow + k0 + sseg * 32;
#pragma unroll
      for (int v = 0; v < 4; ++v) {
        float4 f0 = *reinterpret_cast<const float4*>(pa + v * 8);
        float4 f1 = *reinterpret_cast<const float4*>(pa + v * 8 + 4);
        if (MODE == 2) {
          const float* pa2 = arow2 + k0 + sseg * 32;
          float4 g0 = *reinterpret_cast<const float4*>(pa2 + v * 8);
          float4 g1 = *reinterpret_cast<const float4*>(pa2 + v * 8 + 4);
          f0.x = (f0.x + g0.x) * wgt; f0.y = (f0.y + g0.y) * wgt;
          f0.z = (f0.z + g0.z) * wgt; f0.w = (f0.w + g0.w) * wgt;
          f1.x = (f1.x + g1.x) * wgt; f1.y = (f1.y + g1.y) * wgt;
          f1.z = (f1.z + g1.z) * wgt; f1.w = (f1.w + g1.w) * wgt;
        }
        float bf[8] = {f0.x, f0.y, f0.z, f0.w, f1.x, f1.y, f1.z, f1.w};
        s8v hi, lo;
#pragma unroll
        for (int e = 0; e < 8; ++e) {
          short h = f2bf(bf[e]); hi[e] = h; lo[e] = f2bf(bf[e] - bf2f(h));
        }
        int slot = srow * 8 + ((sseg * 4 + v) ^ (srow & 7));
        *reinterpret_cast<s8v*>(Ah + slot * 8) = hi;
        *reinterpret_cast<s8v*>(Al + slot * 8) = lo;
      }
      const float* pb = brow + k0 + sseg * 32;
#pragma unroll
      for (int v = 0; v < 4; ++v) {
        float4 f0 = *reinterpret_cast<const float4*>(pb + v * 8);
        float4 f1 = *reinterpret_cast<const float4*>(pb + v * 8 + 4);
        float bf[8] = {f0.x, f0.y, f0.z, f0.w, f1.x, f1.y, f1.z, f1.w};
        s8v hi, lo;
#pragma unroll
        for (int e = 0; e < 8; ++e) {
          short h = f2bf(bf[e]); hi[e] = h; lo[e] = f2bf(bf[e] - bf2f(h));
        }
        int slot = srow * 8 + ((sseg * 4 + v) ^ (srow & 7));
        *reinterpret_cast<s8v*>(Bh + slot * 8) = hi;
        *reinterpret_cast<s8v*>(Bl + slot * 8) = lo;
      }
    }
    __syncthreads();
#pragma unroll
    for (int ks = 0; ks < 2; ++ks) {
      s8v a_h[4], a_l[4], b_h[4], b_l[4];
#pragma unroll
      for (int x = 0; x < 4; ++x) {
        int ra = wm * 64 + x * 16 + lr;
        int sa = ra * 8 + ((ks * 4 + lg) ^ (ra & 7));
        a_h[x] = *reinterpret_cast<const s8v*>(Ah + sa * 8);
        a_l[x] = *reinterpret_cast<const s8v*>(Al + sa * 8);
        int rb = wn * 64 + x * 16 + lr;
        int sb = rb * 8 + ((ks * 4 + lg) ^ (rb & 7));
        b_h[x] = *reinterpret_cast<const s8v*>(Bh + sb * 8);
        b_l[x] = *reinterpret_cast<const s8v*>(Bl + sb * 8);
      }
#pragma unroll
      for (int mf = 0; mf < 4; ++mf)
#pragma unroll
        for (int nf = 0; nf < 4; ++nf) {
          acc[mf][nf] = MFMA16(a_l[mf], b_h[nf], acc[mf][nf]);
          acc[mf][nf] = MFMA16(a_h[mf], b_l[nf], acc[mf][nf]);
          acc[mf][nf] = MFMA16(a_h[mf], b_h[nf], acc[mf][nf]);
        }
    }
  }
  // ---- epilogue: C/D layout col=lane&15, row=(lane>>4)*4+reg (m89-verified)
  const int sec = (MODE == 0) ? (n0 >> 10) : 0;
#pragma unroll
  for (int mf = 0; mf < 4; ++mf)
#pragma unroll
    for (int nf = 0; nf < 4; ++nf) {
      const int n = n0 + wn * 64 + nf * 16 + lr;
#pragma unroll
      for (int r = 0; r < 4; ++r) {
        const int m = m0 + wm * 64 + mf * 16 + lg * 4 + r;
        float val = acc[mf][nf][r];
        if (MODE == 2) {
          Ofp[(size_t)m * 1024 + n] = val;
        } else if (MODE == 1) {
          int nn = n >> 6, d = n & 63;
          size_t idx = (((size_t)nn * KL + m) << 6) + d;
          short h = f2bf(val);
          P0h[idx] = h; P0l[idx] = f2bf(val - bf2f(h));
        } else {
          int b = m & 1, t = m >> 1;
          if (sec == 0) {                       // q section: t >= 1024 guaranteed
            int i = t - 1024;
            int nn = n >> 6, d = n & 63;
            size_t idx = (((size_t)(b * NHh + nn) * QL + i) << 6) + d;
            float qw = val + rwb[n];
            float qr = val + rrb[n];
            short h = f2bf(qw);
            P0h[idx] = h; P0l[idx] = f2bf(qw - bf2f(h));
            h = f2bf(qr);
            P1h[idx] = h; P1l[idx] = f2bf(qr - bf2f(h));
          } else if (sec == 1) {                // K
            int c = n - 1024; int nn = c >> 6, d = c & 63;
            size_t idx = (((size_t)(b * NHh + nn) * KL + t) << 6) + d;
            short h = f2bf(val);
            P2h[idx] = h; P2l[idx] = f2bf(val - bf2f(h));
          } else {                              // V^T single bf16 [bn][d][t]
            int c = n - 2048; int nn = c >> 6, d = c & 63;
            size_t idx = ((size_t)(b * NHh + nn) * 64 + d) * KL + t;
            P3[idx] = f2bf(val);
          }
        }
      }
    }
}

// ---------------------------------------------------------------------------
// Fused attention — EXACT r14 shape (226 us proven: 1 wave / 32 q-rows, plain
// launch_bounds(64) -> VGPR~160, inline just-in-time loads, setprio, XCD
// decode, r3-refchecked rel-shift algebra). Only delta vs r14: no l tracking
// (rescale_prob computes row sums itself — r17-proven piece).
// Grid 2048 flat: xcd=orig&7 -> bn, iblk (32x32 rows), ch (2 j-chunks).
// BD rel-shift: G[ir][c] = Qr_i * RK[BASE+c], BASE = 992-i0+j0; mf0 uses
// c in [16,95] (skip ci0), mf1 uses c in [0,79] (skip ci5);
// gather cl = 31 - mf*16 - ir16 + jf*16 + lr.
// ---------------------------------------------------------------------------
__global__ __launch_bounds__(64)
void attn_fused(const short* __restrict__ Qwh, const short* __restrict__ Qwl,
                const short* __restrict__ Qrh, const short* __restrict__ Qrl,
                const short* __restrict__ Kh,  const short* __restrict__ Klo,
                const short* __restrict__ RKh, const short* __restrict__ RKl,
                const short* __restrict__ Vb,
                float* __restrict__ prob,
                float* __restrict__ avp)
{
  __shared__ float Gs[96 * 20];     // [c][i16] fp32, per-mf sequential reuse
  __shared__ short Ps[32 * 72];     // P tile bf16 for PV A-frags
  const int L = threadIdx.x;
  const int lr = L & 15, lg = L >> 4;
  // XCD-locality decode (bijection over 2048 = 8 xcd x 4 bnl x 64 rest)
  const int orig = blockIdx.x;
  const int xcd  = orig & 7;
  const int k2   = orig >> 3;              // 0..255
  const int bn   = xcd * 4 + (k2 >> 6);    // 0..31
  const int rest = k2 & 63;
  const int iblk = rest >> 1, ch = rest & 1;
  const int nh = bn & 15, b = bn >> 4;
  const int i0 = iblk * 32;
  const f4v fz = {0.f, 0.f, 0.f, 0.f};

  int T = ((i0 + 1055) >> 6) + 1; if (T > 32) T = 32;
  const int t0 = (ch * T) >> 1;
  const int t1 = ((ch + 1) * T) >> 1;

  // Q A-frags for both mf halves, held for the whole kernel
  s8v qw_h[2][2], qw_l[2][2], qr_h[2][2], qr_l[2][2];
#pragma unroll
  for (int mf = 0; mf < 2; ++mf)
#pragma unroll
    for (int ks = 0; ks < 2; ++ks) {
      size_t idx = (((size_t)bn * QL + i0 + mf * 16 + lr) << 6) + ks * 32 + lg * 8;
      qw_h[mf][ks] = *reinterpret_cast<const s8v*>(Qwh + idx);
      qw_l[mf][ks] = *reinterpret_cast<const s8v*>(Qwl + idx);
      qr_h[mf][ks] = *reinterpret_cast<const s8v*>(Qrh + idx);
      qr_l[mf][ks] = *reinterpret_cast<const s8v*>(Qrl + idx);
    }

  f4v av[2][4];
#pragma unroll
  for (int mf = 0; mf < 2; ++mf)
#pragma unroll
    for (int r = 0; r < 4; ++r) av[mf][r] = fz;

  float* probb = prob + (size_t)bn * QL * KL;

  for (int jt = t0; jt < t1; ++jt) {
    const int j0 = jt * 64;
    const int BASE = 992 - i0 + j0;
    // ---- BD window GEMM (inline loads, shared across both mf)
    f4v gacc[2][5];
#pragma unroll
    for (int mf = 0; mf < 2; ++mf)
#pragma unroll
      for (int gi = 0; gi < 5; ++gi) gacc[mf][gi] = fz;
    __builtin_amdgcn_s_setprio(1);
#pragma unroll
    for (int ci = 0; ci < 6; ++ci) {
      int rg = BASE + ci * 16 + lr;
      rg = rg < 0 ? 0 : (rg > 2047 ? 2047 : rg);  // clamped rows feed masked elems only
      size_t ridx = ((size_t)nh * KL + rg) << 6;
      s8v r_h[2], r_l[2];
#pragma unroll
      for (int ks = 0; ks < 2; ++ks) {
        r_h[ks] = *reinterpret_cast<const s8v*>(RKh + ridx + ks * 32 + lg * 8);
        r_l[ks] = *reinterpret_cast<const s8v*>(RKl + ridx + ks * 32 + lg * 8);
      }
#pragma unroll
      for (int mf = 0; mf < 2; ++mf) {
        if (mf == 0 && ci == 0) continue;   // mf0 uses c in [16,95]
        if (mf == 1 && ci == 5) continue;   // mf1 uses c in [0,79]
        const int gi = (mf == 0) ? (ci - 1) : ci;
#pragma unroll
        for (int ks = 0; ks < 2; ++ks) {
          gacc[mf][gi] = MFMA16(qr_l[mf][ks], r_h[ks], gacc[mf][gi]);
          gacc[mf][gi] = MFMA16(qr_h[mf][ks], r_l[ks], gacc[mf][gi]);
          gacc[mf][gi] = MFMA16(qr_h[mf][ks], r_h[ks], gacc[mf][gi]);
        }
      }
    }
    __builtin_amdgcn_s_setprio(0);
    // ---- per mf: spill G, AC GEMM (inline K loads), gather+exp+write
#pragma unroll
    for (int mf = 0; mf < 2; ++mf) {
#pragma unroll
      for (int gi = 0; gi < 5; ++gi) {
        int c = (mf == 0 ? 16 : 0) + gi * 16 + lr;
        *reinterpret_cast<f4v*>(Gs + c * 20 + lg * 4) = gacc[mf][gi];
      }
      f4v sfr[4];
      __builtin_amdgcn_s_setprio(1);
#pragma unroll
      for (int jf = 0; jf < 4; ++jf) {
        sfr[jf] = fz;
        size_t kidx = ((size_t)bn * KL + j0 + jf * 16 + lr) << 6;
#pragma unroll
        for (int ks = 0; ks < 2; ++ks) {
          s8v k_h = *reinterpret_cast<const s8v*>(Kh  + kidx + ks * 32 + lg * 8);
          s8v k_l = *reinterpret_cast<const s8v*>(Klo + kidx + ks * 32 + lg * 8);
          sfr[jf] = MFMA16(qw_l[mf][ks], k_h, sfr[jf]);
          sfr[jf] = MFMA16(qw_h[mf][ks], k_l, sfr[jf]);
          sfr[jf] = MFMA16(qw_h[mf][ks], k_h, sfr[jf]);
        }
      }
      __builtin_amdgcn_s_setprio(0);
#pragma unroll
      for (int jf = 0; jf < 4; ++jf) {
#pragma unroll
        for (int r = 0; r < 4; ++r) {
          const int ir16 = lg * 4 + r;
          const int i = i0 + mf * 16 + ir16;
          const int j = j0 + jf * 16 + lr;
          const int cl = 31 - mf * 16 - ir16 + jf * 16 + lr;
          float s = (sfr[jf][r] + Gs[cl * 20 + ir16]) * SCALEh;
          float p = (j <= i + 1024) ? __expf(s) : 0.f;
          probb[(size_t)i * KL + j] = p;
          Ps[(mf * 16 + ir16) * 72 + jf * 16 + lr] = f2bf(p);
        }
      }
    }
    // ---- PV: inline V loads shared across both mf
    __builtin_amdgcn_s_setprio(1);
#pragma unroll
    for (int ks = 0; ks < 2; ++ks) {
      s8v pa[2];
#pragma unroll
      for (int mf = 0; mf < 2; ++mf)
        pa[mf] = *reinterpret_cast<const s8v*>(Ps + (mf * 16 + lr) * 72 + ks * 32 + lg * 8);
#pragma unroll
      for (int df = 0; df < 4; ++df) {
        s8v vfr = *reinterpret_cast<const s8v*>(
            Vb + ((size_t)bn * 64 + df * 16 + lr) * KL + j0 + ks * 32 + lg * 8);
#pragma unroll
        for (int mf = 0; mf < 2; ++mf)
          av[mf][df] = MFMA16(pa[mf], vfr, av[mf][df]);
      }
    }
    __builtin_amdgcn_s_setprio(0);
  }

  // ---- AV' partials
#pragma unroll
  for (int mf = 0; mf < 2; ++mf)
#pragma unroll
    for (int df = 0; df < 4; ++df)
#pragma unroll
      for (int r = 0; r < 4; ++r) {
        int i = i0 + mf * 16 + lg * 4 + r;
        int d = df * 16 + lr;
        avp[(size_t)ch * 2097152 + ((size_t)i * 2 + b) * 1024 + nh * 64 + d] = av[mf][df][r];
      }
}

// ---------------------------------------------------------------------------
// prob[row][j] = p'[row][j] / l_row for valid j (else exact 0), where
// l_row = sum_j p'. Computes the row sum itself, skips reading fully-masked
// chunks, writes the full row (zeros in masked region), and emits linv.
// ---------------------------------------------------------------------------
__global__ __launch_bounds__(256)
void rescale_prob(float* __restrict__ prob, float* __restrict__ linv)
{
  __shared__ float red[8];
  const int row = blockIdx.x;                 // bn*1024 + i
  const int i = row & 1023;
  const int lim = i + 1024;                   // j <= lim valid
  const int tid = threadIdx.x;
  const int jb = tid * 8;
  float* p = prob + ((size_t)row << 11) + jb;

  float4 a = {0.f, 0.f, 0.f, 0.f}, c = {0.f, 0.f, 0.f, 0.f};
  if (jb <= lim) {                            // at least one valid element
    a = *reinterpret_cast<const float4*>(p);
    c = *reinterpret_cast<const float4*>(p + 4);
    if (jb + 1 > lim) a.y = 0.f;
    if (jb + 2 > lim) a.z = 0.f;
    if (jb + 3 > lim) a.w = 0.f;
    if (jb + 4 > lim) c.x = 0.f;
    if (jb + 5 > lim) c.y = 0.f;
    if (jb + 6 > lim) c.z = 0.f;
    if (jb + 7 > lim) c.w = 0.f;
  }
  float sum = a.x + a.y + a.z + a.w + c.x + c.y + c.z + c.w;
#pragma unroll
  for (int mk = 1; mk <= 32; mk <<= 1) sum += __shfl_xor(sum, mk, 64);
  if ((tid & 63) == 0) red[tid >> 6] = sum;
  __syncthreads();
  float l = red[0] + red[1] + red[2] + red[3];
  float wgt = 1.0f / l;
  if (tid == 0) linv[row] = wgt;

  a.x *= wgt; a.y *= wgt; a.z *= wgt; a.w *= wgt;
  c.x *= wgt; c.y *= wgt; c.z *= wgt; c.w *= wgt;
  *reinterpret_cast<float4*>(p) = a;
  *reinterpret_cast<float4*>(p + 4) = c;
}

// ---------------------------------------------------------------------------
extern "C" void kernel_launch(void* const* d_in, const int* in_sizes, int n_in,
                              void* d_out, int out_size, void* d_ws, size_t ws_size,
                              hipStream_t stream)
{
  (void)in_sizes; (void)n_in; (void)out_size; (void)ws_size;
  const float* w    = (const float*)d_in[0];
  const float* r    = (const float*)d_in[1];
  const float* rwb  = (const float*)d_in[2];
  const float* rrb  = (const float*)d_in[3];
  const float* mems = (const float*)d_in[4];
  const float* Wqkv = (const float*)d_in[5];
  const float* Wr   = (const float*)d_in[6];
  const float* Wo   = (const float*)d_in[7];

  float* out  = (float*)d_out;
  float* prob = out + 2097152;

  // convert_k scratch lives in the prob region (256 MB) — written and fully
  // consumed by gemm0 BEFORE attn overwrites prob (stream-ordered).
  short* Abf_h = (short*)prob;              // 4096x1024
  short* Abf_l = Abf_h + 4194304;
  short* Bbf_h = Abf_l + 4194304;           // 3072x1024
  short* Bbf_l = Bbf_h + 3145728;

  // workspace: 67,371,008 B total (identical to the round-1/14 passing layout)
  short* Qwh = (short*)d_ws;
  short* Qwl = Qwh + 2097152;
  short* Qrh = Qwl + 2097152;
  short* Qrl = Qrh + 2097152;
  short* Kh  = Qrl + 2097152;
  short* Klo = Kh  + 4194304;
  short* Vb  = Klo + 4194304;
  short* RKh = Vb  + 4194304;
  short* RKl = RKh + 2097152;
  float* avp  = (float*)(RKl + 2097152);    // 2 x 2,097,152 floats
  float* linv = avp + 4194304;              // 32,768 floats

  convert_k<<<dim3(7168), 256, 0, stream>>>(
      mems, w, Wqkv, Abf_h, Abf_l, Bbf_h, Bbf_l);
  gemm_mfma<0><<<dim3(24, 32), 256, 0, stream>>>(
      nullptr, nullptr, nullptr, Abf_h, Abf_l, Bbf_h, Bbf_l,
      Qwh, Qwl, Qrh, Qrl, Kh, Klo, Vb, nullptr, rwb, rrb, nullptr);
  gemm_mfma<1><<<dim3(8, 16), 256, 0, stream>>>(
      r, nullptr, Wr, nullptr, nullptr, nullptr, nullptr,
      RKh, RKl, nullptr, nullptr, nullptr, nullptr, nullptr,
      nullptr, nullptr, nullptr, nullptr);
  attn_fused<<<dim3(2048), 64, 0, stream>>>(
      Qwh, Qwl, Qrh, Qrl, Kh, Klo, RKh, RKl, Vb, prob, avp);
  rescale_prob<<<32768, 256, 0, stream>>>(prob, linv);
  gemm_mfma<2><<<dim3(8, 16), 256, 0, stream>>>(
      avp, avp + 2097152, Wo, nullptr, nullptr, nullptr, nullptr,
      nullptr, nullptr, nullptr, nullptr, nullptr, nullptr, nullptr,
      out, nullptr, nullptr, linv);
}

// Round 19
// 541.974 us; speedup vs baseline: 1.8089x; 1.0156x over previous
//
#include <hip/hip_runtime.h>
#include <math.h>

#define NHh   16
#define QL    1024
#define KL    2048
#define SCALEh 0.125f

typedef __attribute__((ext_vector_type(8))) short s8v;
typedef __attribute__((ext_vector_type(4))) short s4v;
typedef __attribute__((ext_vector_type(4))) float f4v;

#define MFMA16(a,b,c) __builtin_amdgcn_mfma_f32_16x16x32_bf16((a),(b),(c),0,0,0)

__device__ __forceinline__ short f2bf(float x) {
  unsigned u = __float_as_uint(x);
  return (short)((u + 0x7fffu + ((u >> 16) & 1u)) >> 16);
}
__device__ __forceinline__ float bf2f(short s) {
  return __uint_as_float(((unsigned)(unsigned short)s) << 16);
}

// ---------------------------------------------------------------------------
// One-shot fp32 -> split-bf16 (hi/lo) conversion of gemm0 operands.
// Row r < 4096: A = [mems;w] row; else B = Wqkv row (r-4096). One row/block.
// ---------------------------------------------------------------------------
__global__ __launch_bounds__(256)
void convert_k(const float* __restrict__ mems, const float* __restrict__ w,
               const float* __restrict__ Wqkv,
               short* __restrict__ Ah, short* __restrict__ Al,
               short* __restrict__ Bh, short* __restrict__ Bl)
{
  const int row = blockIdx.x;
  const int t = threadIdx.x;            // 256 threads x 4 elems = 1024
  const float* src;
  short *dh, *dl;
  size_t r2;
  if (row < 4096) {
    src = (row < 2048) ? (mems + (size_t)row * 1024)
                       : (w + (size_t)(row - 2048) * 1024);
    dh = Ah; dl = Al; r2 = row;
  } else {
    src = Wqkv + (size_t)(row - 4096) * 1024;
    dh = Bh; dl = Bl; r2 = row - 4096;
  }
  float4 v = *reinterpret_cast<const float4*>(src + t * 4);
  short h0 = f2bf(v.x), h1 = f2bf(v.y), h2 = f2bf(v.z), h3 = f2bf(v.w);
  s4v hi = {h0, h1, h2, h3};
  s4v lo = {f2bf(v.x - bf2f(h0)), f2bf(v.y - bf2f(h1)),
            f2bf(v.z - bf2f(h2)), f2bf(v.w - bf2f(h3))};
  *reinterpret_cast<s4v*>(dh + r2 * 1024 + t * 4) = hi;
  *reinterpret_cast<s4v*>(dl + r2 * 1024 + t * 4) = lo;
}

// ---------------------------------------------------------------------------
// split-bf16 MFMA GEMM: C[m][n] = sum_k A[m][k]*Bmat[n][k], K=1024, tile 128x128
// MODE0: A/B pre-converted bf16 hi/lo (SA*/SB*); staging via ASYNC
//        global_load_lds width=16 (m97: +67% on this structure) — wave w
//        stages region w (Ah/Al/Bh/Bl); XOR slot swizzle carried by the
//        per-lane GLOBAL source address (m173): slot s -> row=s>>3,
//        kg=(s&7)^(row&7); LDS dest = region base + e*512 shorts (uniform),
//        HW adds lane*16B. Epilogue: Qw/Qr hi/lo (+bias), K hi/lo, V^T bf16.
// MODE1: A=r fp32 (inline convert); epilogue: RK hi/lo [head][row][d]
// MODE2: A=(avp0+avp1)*linv_row fp32; epilogue: out fp32
// ---------------------------------------------------------------------------
template<int MODE>
__global__ __launch_bounds__(256)
void gemm_mfma(const float* __restrict__ A0, const float* __restrict__ A1,
               const float* __restrict__ Bmat,
               const short* __restrict__ SAh, const short* __restrict__ SAl,
               const short* __restrict__ SBh, const short* __restrict__ SBl,
               short* __restrict__ P0h, short* __restrict__ P0l,
               short* __restrict__ P1h, short* __restrict__ P1l,
               short* __restrict__ P2h, short* __restrict__ P2l,
               short* __restrict__ P3,
               float* __restrict__ Ofp,
               const float* __restrict__ rwb, const float* __restrict__ rrb,
               const float* __restrict__ Wl)
{
  __shared__ short Ah[128*64];
  __shared__ short Al[128*64];
  __shared__ short Bh[128*64];
  __shared__ short Bl[128*64];
  const int n0 = blockIdx.x * 128, m0 = blockIdx.y * 128;
  if (MODE == 0 && n0 < 1024 && m0 < 2048) return;   // q rows t<1024 are discarded
  const int tid = threadIdx.x;
  const int L = tid & 63, lr = L & 15, lg = L >> 4;
  const int wid = tid >> 6, wm = wid >> 1, wn = wid & 1;
  const int srow = tid >> 1, sseg = tid & 1;

  const float* arow = nullptr;
  const float* arow2 = nullptr;
  const short* stgsrc = nullptr;
  short* stgdst = nullptr;
  int stgrow0 = 0;
  if (MODE == 0) {
    // wave wid stages one region
    if (wid == 0)      { stgsrc = SAh; stgdst = Ah; stgrow0 = m0; }
    else if (wid == 1) { stgsrc = SAl; stgdst = Al; stgrow0 = m0; }
    else if (wid == 2) { stgsrc = SBh; stgdst = Bh; stgrow0 = n0; }
    else               { stgsrc = SBl; stgdst = Bl; stgrow0 = n0; }
  } else {
    arow = A0 + (size_t)(m0 + srow) * 1024;
    if (MODE == 2) arow2 = A1 + (size_t)(m0 + srow) * 1024;
  }
  const float* brow = (MODE == 0) ? nullptr : (Bmat + (size_t)(n0 + srow) * 1024);

  const f4v fz = {0.f, 0.f, 0.f, 0.f};
  f4v acc[4][4];
#pragma unroll
  for (int a = 0; a < 4; ++a)
#pragma unroll
    for (int bq = 0; bq < 4; ++bq) acc[a][bq] = fz;

  for (int k0 = 0; k0 < 1024; k0 += 64) {
    __syncthreads();
    if (MODE == 0) {
#pragma unroll
      for (int e = 0; e < 16; ++e) {
        int s2 = e * 64 + L;                     // slot within region
        int row = s2 >> 3, kg = (s2 & 7) ^ (row & 7);
        const short* src = stgsrc + (size_t)(stgrow0 + row) * 1024 + k0 + kg * 8;
        __builtin_amdgcn_global_load_lds(
            (const __attribute__((address_space(1))) void*)src,
            (__attribute__((address_space(3))) void*)(stgdst + (size_t)e * 512),
            16, 0, 0);
      }
    } else {
      float wgt = 1.0f;
      if (MODE == 2) {
        int m = m0 + srow;
        wgt = Wl[((size_t)((m & 1) * NHh) + (k0 >> 6)) * 1024 + (m >> 1)];
      }
      const float* pa = arow + k0 + sseg * 32;
#pragma unroll
      for (int v = 0; v < 4; ++v) {
        float4 f0 = *reinterpret_cast<const float4*>(pa + v * 8);
        float4 f1 = *reinterpret_cast<const float4*>(pa + v * 8 + 4);
        if (MODE == 2) {
          const float* pa2 = arow2 + k0 + sseg * 32;
          float4 g0 = *reinterpret_cast<const float4*>(pa2 + v * 8);
          float4 g1 = *reinterpret_cast<const float4*>(pa2 + v * 8 + 4);
          f0.x = (f0.x + g0.x) * wgt; f0.y = (f0.y + g0.y) * wgt;
          f0.z = (f0.z + g0.z) * wgt; f0.w = (f0.w + g0.w) * wgt;
          f1.x = (f1.x + g1.x) * wgt; f1.y = (f1.y + g1.y) * wgt;
          f1.z = (f1.z + g1.z) * wgt; f1.w = (f1.w + g1.w) * wgt;
        }
        float bf[8] = {f0.x, f0.y, f0.z, f0.w, f1.x, f1.y, f1.z, f1.w};
        s8v hi, lo;
#pragma unroll
        for (int e = 0; e < 8; ++e) {
          short h = f2bf(bf[e]); hi[e] = h; lo[e] = f2bf(bf[e] - bf2f(h));
        }
        int slot = srow * 8 + ((sseg * 4 + v) ^ (srow & 7));
        *reinterpret_cast<s8v*>(Ah + slot * 8) = hi;
        *reinterpret_cast<s8v*>(Al + slot * 8) = lo;
      }
      const float* pb = brow + k0 + sseg * 32;
#pragma unroll
      for (int v = 0; v < 4; ++v) {
        float4 f0 = *reinterpret_cast<const float4*>(pb + v * 8);
        float4 f1 = *reinterpret_cast<const float4*>(pb + v * 8 + 4);
        float bf[8] = {f0.x, f0.y, f0.z, f0.w, f1.x, f1.y, f1.z, f1.w};
        s8v hi, lo;
#pragma unroll
        for (int e = 0; e < 8; ++e) {
          short h = f2bf(bf[e]); hi[e] = h; lo[e] = f2bf(bf[e] - bf2f(h));
        }
        int slot = srow * 8 + ((sseg * 4 + v) ^ (srow & 7));
        *reinterpret_cast<s8v*>(Bh + slot * 8) = hi;
        *reinterpret_cast<s8v*>(Bl + slot * 8) = lo;
      }
    }
    __syncthreads();
#pragma unroll
    for (int ks = 0; ks < 2; ++ks) {
      s8v a_h[4], a_l[4], b_h[4], b_l[4];
#pragma unroll
      for (int x = 0; x < 4; ++x) {
        int ra = wm * 64 + x * 16 + lr;
        int sa = ra * 8 + ((ks * 4 + lg) ^ (ra & 7));
        a_h[x] = *reinterpret_cast<const s8v*>(Ah + sa * 8);
        a_l[x] = *reinterpret_cast<const s8v*>(Al + sa * 8);
        int rb = wn * 64 + x * 16 + lr;
        int sb = rb * 8 + ((ks * 4 + lg) ^ (rb & 7));
        b_h[x] = *reinterpret_cast<const s8v*>(Bh + sb * 8);
        b_l[x] = *reinterpret_cast<const s8v*>(Bl + sb * 8);
      }
#pragma unroll
      for (int mf = 0; mf < 4; ++mf)
#pragma unroll
        for (int nf = 0; nf < 4; ++nf) {
          acc[mf][nf] = MFMA16(a_l[mf], b_h[nf], acc[mf][nf]);
          acc[mf][nf] = MFMA16(a_h[mf], b_l[nf], acc[mf][nf]);
          acc[mf][nf] = MFMA16(a_h[mf], b_h[nf], acc[mf][nf]);
        }
    }
  }
  // ---- epilogue: C/D layout col=lane&15, row=(lane>>4)*4+reg (m89-verified)
  const int sec = (MODE == 0) ? (n0 >> 10) : 0;
#pragma unroll
  for (int mf = 0; mf < 4; ++mf)
#pragma unroll
    for (int nf = 0; nf < 4; ++nf) {
      const int n = n0 + wn * 64 + nf * 16 + lr;
#pragma unroll
      for (int r = 0; r < 4; ++r) {
        const int m = m0 + wm * 64 + mf * 16 + lg * 4 + r;
        float val = acc[mf][nf][r];
        if (MODE == 2) {
          Ofp[(size_t)m * 1024 + n] = val;
        } else if (MODE == 1) {
          int nn = n >> 6, d = n & 63;
          size_t idx = (((size_t)nn * KL + m) << 6) + d;
          short h = f2bf(val);
          P0h[idx] = h; P0l[idx] = f2bf(val - bf2f(h));
        } else {
          int b = m & 1, t = m >> 1;
          if (sec == 0) {                       // q section: t >= 1024 guaranteed
            int i = t - 1024;
            int nn = n >> 6, d = n & 63;
            size_t idx = (((size_t)(b * NHh + nn) * QL + i) << 6) + d;
            float qw = val + rwb[n];
            float qr = val + rrb[n];
            short h = f2bf(qw);
            P0h[idx] = h; P0l[idx] = f2bf(qw - bf2f(h));
            h = f2bf(qr);
            P1h[idx] = h; P1l[idx] = f2bf(qr - bf2f(h));
          } else if (sec == 1) {                // K
            int c = n - 1024; int nn = c >> 6, d = c & 63;
            size_t idx = (((size_t)(b * NHh + nn) * KL + t) << 6) + d;
            short h = f2bf(val);
            P2h[idx] = h; P2l[idx] = f2bf(val - bf2f(h));
          } else {                              // V^T single bf16 [bn][d][t]
            int c = n - 2048; int nn = c >> 6, d = c & 63;
            size_t idx = ((size_t)(b * NHh + nn) * 64 + d) * KL + t;
            P3[idx] = f2bf(val);
          }
        }
      }
    }
}

// ---------------------------------------------------------------------------
// Fused attention — EXACT r14 shape (223 us proven: 1 wave / 32 q-rows, plain
// launch_bounds(64) -> VGPR~152, inline just-in-time loads, setprio, XCD
// decode, r3-refchecked rel-shift algebra). No l tracking (rescale_prob
// computes row sums itself).
// Grid 2048 flat: xcd=orig&7 -> bn, iblk (32x32 rows), ch (2 j-chunks).
// BD rel-shift: G[ir][c] = Qr_i * RK[BASE+c], BASE = 992-i0+j0; mf0 uses
// c in [16,95] (skip ci0), mf1 uses c in [0,79] (skip ci5);
// gather cl = 31 - mf*16 - ir16 + jf*16 + lr.
// ---------------------------------------------------------------------------
__global__ __launch_bounds__(64)
void attn_fused(const short* __restrict__ Qwh, const short* __restrict__ Qwl,
                const short* __restrict__ Qrh, const short* __restrict__ Qrl,
                const short* __restrict__ Kh,  const short* __restrict__ Klo,
                const short* __restrict__ RKh, const short* __restrict__ RKl,
                const short* __restrict__ Vb,
                float* __restrict__ prob,
                float* __restrict__ avp)
{
  __shared__ float Gs[96 * 20];     // [c][i16] fp32, per-mf sequential reuse
  __shared__ short Ps[32 * 72];     // P tile bf16 for PV A-frags
  const int L = threadIdx.x;
  const int lr = L & 15, lg = L >> 4;
  // XCD-locality decode (bijection over 2048 = 8 xcd x 4 bnl x 64 rest)
  const int orig = blockIdx.x;
  const int xcd  = orig & 7;
  const int k2   = orig >> 3;              // 0..255
  const int bn   = xcd * 4 + (k2 >> 6);    // 0..31
  const int rest = k2 & 63;
  const int iblk = rest >> 1, ch = rest & 1;
  const int nh = bn & 15, b = bn >> 4;
  const int i0 = iblk * 32;
  const f4v fz = {0.f, 0.f, 0.f, 0.f};

  int T = ((i0 + 1055) >> 6) + 1; if (T > 32) T = 32;
  const int t0 = (ch * T) >> 1;
  const int t1 = ((ch + 1) * T) >> 1;

  // Q A-frags for both mf halves, held for the whole kernel
  s8v qw_h[2][2], qw_l[2][2], qr_h[2][2], qr_l[2][2];
#pragma unroll
  for (int mf = 0; mf < 2; ++mf)
#pragma unroll
    for (int ks = 0; ks < 2; ++ks) {
      size_t idx = (((size_t)bn * QL + i0 + mf * 16 + lr) << 6) + ks * 32 + lg * 8;
      qw_h[mf][ks] = *reinterpret_cast<const s8v*>(Qwh + idx);
      qw_l[mf][ks] = *reinterpret_cast<const s8v*>(Qwl + idx);
      qr_h[mf][ks] = *reinterpret_cast<const s8v*>(Qrh + idx);
      qr_l[mf][ks] = *reinterpret_cast<const s8v*>(Qrl + idx);
    }

  f4v av[2][4];
#pragma unroll
  for (int mf = 0; mf < 2; ++mf)
#pragma unroll
    for (int r = 0; r < 4; ++r) av[mf][r] = fz;

  float* probb = prob + (size_t)bn * QL * KL;

  for (int jt = t0; jt < t1; ++jt) {
    const int j0 = jt * 64;
    const int BASE = 992 - i0 + j0;
    // ---- BD window GEMM (inline loads, shared across both mf)
    f4v gacc[2][5];
#pragma unroll
    for (int mf = 0; mf < 2; ++mf)
#pragma unroll
      for (int gi = 0; gi < 5; ++gi) gacc[mf][gi] = fz;
    __builtin_amdgcn_s_setprio(1);
#pragma unroll
    for (int ci = 0; ci < 6; ++ci) {
      int rg = BASE + ci * 16 + lr;
      rg = rg < 0 ? 0 : (rg > 2047 ? 2047 : rg);  // clamped rows feed masked elems only
      size_t ridx = ((size_t)nh * KL + rg) << 6;
      s8v r_h[2], r_l[2];
#pragma unroll
      for (int ks = 0; ks < 2; ++ks) {
        r_h[ks] = *reinterpret_cast<const s8v*>(RKh + ridx + ks * 32 + lg * 8);
        r_l[ks] = *reinterpret_cast<const s8v*>(RKl + ridx + ks * 32 + lg * 8);
      }
#pragma unroll
      for (int mf = 0; mf < 2; ++mf) {
        if (mf == 0 && ci == 0) continue;   // mf0 uses c in [16,95]
        if (mf == 1 && ci == 5) continue;   // mf1 uses c in [0,79]
        const int gi = (mf == 0) ? (ci - 1) : ci;
#pragma unroll
        for (int ks = 0; ks < 2; ++ks) {
          gacc[mf][gi] = MFMA16(qr_l[mf][ks], r_h[ks], gacc[mf][gi]);
          gacc[mf][gi] = MFMA16(qr_h[mf][ks], r_l[ks], gacc[mf][gi]);
          gacc[mf][gi] = MFMA16(qr_h[mf][ks], r_h[ks], gacc[mf][gi]);
        }
      }
    }
    __builtin_amdgcn_s_setprio(0);
    // ---- per mf: spill G, AC GEMM (inline K loads), gather+exp+write
#pragma unroll
    for (int mf = 0; mf < 2; ++mf) {
#pragma unroll
      for (int gi = 0; gi < 5; ++gi) {
        int c = (mf == 0 ? 16 : 0) + gi * 16 + lr;
        *reinterpret_cast<f4v*>(Gs + c * 20 + lg * 4) = gacc[mf][gi];
      }
      f4v sfr[4];
      __builtin_amdgcn_s_setprio(1);
#pragma unroll
      for (int jf = 0; jf < 4; ++jf) {
        sfr[jf] = fz;
        size_t kidx = ((size_t)bn * KL + j0 + jf * 16 + lr) << 6;
#pragma unroll
        for (int ks = 0; ks < 2; ++ks) {
          s8v k_h = *reinterpret_cast<const s8v*>(Kh  + kidx + ks * 32 + lg * 8);
          s8v k_l = *reinterpret_cast<const s8v*>(Klo + kidx + ks * 32 + lg * 8);
          sfr[jf] = MFMA16(qw_l[mf][ks], k_h, sfr[jf]);
          sfr[jf] = MFMA16(qw_h[mf][ks], k_l, sfr[jf]);
          sfr[jf] = MFMA16(qw_h[mf][ks], k_h, sfr[jf]);
        }
      }
      __builtin_amdgcn_s_setprio(0);
#pragma unroll
      for (int jf = 0; jf < 4; ++jf) {
#pragma unroll
        for (int r = 0; r < 4; ++r) {
          const int ir16 = lg * 4 + r;
          const int i = i0 + mf * 16 + ir16;
          const int j = j0 + jf * 16 + lr;
          const int cl = 31 - mf * 16 - ir16 + jf * 16 + lr;
          float s = (sfr[jf][r] + Gs[cl * 20 + ir16]) * SCALEh;
          float p = (j <= i + 1024) ? __expf(s) : 0.f;
          probb[(size_t)i * KL + j] = p;
          Ps[(mf * 16 + ir16) * 72 + jf * 16 + lr] = f2bf(p);
        }
      }
    }
    // ---- PV: inline V loads shared across both mf
    __builtin_amdgcn_s_setprio(1);
#pragma unroll
    for (int ks = 0; ks < 2; ++ks) {
      s8v pa[2];
#pragma unroll
      for (int mf = 0; mf < 2; ++mf)
        pa[mf] = *reinterpret_cast<const s8v*>(Ps + (mf * 16 + lr) * 72 + ks * 32 + lg * 8);
#pragma unroll
      for (int df = 0; df < 4; ++df) {
        s8v vfr = *reinterpret_cast<const s8v*>(
            Vb + ((size_t)bn * 64 + df * 16 + lr) * KL + j0 + ks * 32 + lg * 8);
#pragma unroll
        for (int mf = 0; mf < 2; ++mf)
          av[mf][df] = MFMA16(pa[mf], vfr, av[mf][df]);
      }
    }
    __builtin_amdgcn_s_setprio(0);
  }

  // ---- AV' partials
#pragma unroll
  for (int mf = 0; mf < 2; ++mf)
#pragma unroll
    for (int df = 0; df < 4; ++df)
#pragma unroll
      for (int r = 0; r < 4; ++r) {
        int i = i0 + mf * 16 + lg * 4 + r;
        int d = df * 16 + lr;
        avp[(size_t)ch * 2097152 + ((size_t)i * 2 + b) * 1024 + nh * 64 + d] = av[mf][df][r];
      }
}

// ---------------------------------------------------------------------------
// prob[row][j] = p'[row][j] / l_row for valid j (else exact 0), where
// l_row = sum_j p'. Computes the row sum itself, skips reading fully-masked
// chunks, writes the full row (zeros in masked region), and emits linv.
// ---------------------------------------------------------------------------
__global__ __launch_bounds__(256)
void rescale_prob(float* __restrict__ prob, float* __restrict__ linv)
{
  __shared__ float red[8];
  const int row = blockIdx.x;                 // bn*1024 + i
  const int i = row & 1023;
  const int lim = i + 1024;                   // j <= lim valid
  const int tid = threadIdx.x;
  const int jb = tid * 8;
  float* p = prob + ((size_t)row << 11) + jb;

  float4 a = {0.f, 0.f, 0.f, 0.f}, c = {0.f, 0.f, 0.f, 0.f};
  if (jb <= lim) {                            // at least one valid element
    a = *reinterpret_cast<const float4*>(p);
    c = *reinterpret_cast<const float4*>(p + 4);
    if (jb + 1 > lim) a.y = 0.f;
    if (jb + 2 > lim) a.z = 0.f;
    if (jb + 3 > lim) a.w = 0.f;
    if (jb + 4 > lim) c.x = 0.f;
    if (jb + 5 > lim) c.y = 0.f;
    if (jb + 6 > lim) c.z = 0.f;
    if (jb + 7 > lim) c.w = 0.f;
  }
  float sum = a.x + a.y + a.z + a.w + c.x + c.y + c.z + c.w;
#pragma unroll
  for (int mk = 1; mk <= 32; mk <<= 1) sum += __shfl_xor(sum, mk, 64);
  if ((tid & 63) == 0) red[tid >> 6] = sum;
  __syncthreads();
  float l = red[0] + red[1] + red[2] + red[3];
  float wgt = 1.0f / l;
  if (tid == 0) linv[row] = wgt;

  a.x *= wgt; a.y *= wgt; a.z *= wgt; a.w *= wgt;
  c.x *= wgt; c.y *= wgt; c.z *= wgt; c.w *= wgt;
  *reinterpret_cast<float4*>(p) = a;
  *reinterpret_cast<float4*>(p + 4) = c;
}

// ---------------------------------------------------------------------------
extern "C" void kernel_launch(void* const* d_in, const int* in_sizes, int n_in,
                              void* d_out, int out_size, void* d_ws, size_t ws_size,
                              hipStream_t stream)
{
  (void)in_sizes; (void)n_in; (void)out_size; (void)ws_size;
  const float* w    = (const float*)d_in[0];
  const float* r    = (const float*)d_in[1];
  const float* rwb  = (const float*)d_in[2];
  const float* rrb  = (const float*)d_in[3];
  const float* mems = (const float*)d_in[4];
  const float* Wqkv = (const float*)d_in[5];
  const float* Wr   = (const float*)d_in[6];
  const float* Wo   = (const float*)d_in[7];

  float* out  = (float*)d_out;
  float* prob = out + 2097152;

  // convert_k scratch lives in the prob region (256 MB) — written and fully
  // consumed by gemm0 BEFORE attn overwrites prob (stream-ordered).
  short* Abf_h = (short*)prob;              // 4096x1024
  short* Abf_l = Abf_h + 4194304;
  short* Bbf_h = Abf_l + 4194304;           // 3072x1024
  short* Bbf_l = Bbf_h + 3145728;

  // workspace: 67,371,008 B total (identical to the round-1/14 passing layout)
  short* Qwh = (short*)d_ws;
  short* Qwl = Qwh + 2097152;
  short* Qrh = Qwl + 2097152;
  short* Qrl = Qrh + 2097152;
  short* Kh  = Qrl + 2097152;
  short* Klo = Kh  + 4194304;
  short* Vb  = Klo + 4194304;
  short* RKh = Vb  + 4194304;
  short* RKl = RKh + 2097152;
  float* avp  = (float*)(RKl + 2097152);    // 2 x 2,097,152 floats
  float* linv = avp + 4194304;              // 32,768 floats

  convert_k<<<dim3(7168), 256, 0, stream>>>(
      mems, w, Wqkv, Abf_h, Abf_l, Bbf_h, Bbf_l);
  gemm_mfma<0><<<dim3(24, 32), 256, 0, stream>>>(
      nullptr, nullptr, nullptr, Abf_h, Abf_l, Bbf_h, Bbf_l,
      Qwh, Qwl, Qrh, Qrl, Kh, Klo, Vb, nullptr, rwb, rrb, nullptr);
  gemm_mfma<1><<<dim3(8, 16), 256, 0, stream>>>(
      r, nullptr, Wr, nullptr, nullptr, nullptr, nullptr,
      RKh, RKl, nullptr, nullptr, nullptr, nullptr, nullptr,
      nullptr, nullptr, nullptr, nullptr);
  attn_fused<<<dim3(2048), 64, 0, stream>>>(
      Qwh, Qwl, Qrh, Qrl, Kh, Klo, RKh, RKl, Vb, prob, avp);
  rescale_prob<<<32768, 256, 0, stream>>>(prob, linv);
  gemm_mfma<2><<<dim3(8, 16), 256, 0, stream>>>(
      avp, avp + 2097152, Wo, nullptr, nullptr, nullptr, nullptr,
      nullptr, nullptr, nullptr, nullptr, nullptr, nullptr, nullptr,
      out, nullptr, nullptr, linv);
}

// Round 20
// 484.696 us; speedup vs baseline: 2.0226x; 1.1182x over previous
//
#include <hip/hip_runtime.h>
#include <math.h>

#define NHh   16
#define QL    1024
#define KL    2048
#define SCALEh 0.125f

typedef __attribute__((ext_vector_type(8))) short s8v;
typedef __attribute__((ext_vector_type(4))) short s4v;
typedef __attribute__((ext_vector_type(4))) float f4v;

#define MFMA16(a,b,c) __builtin_amdgcn_mfma_f32_16x16x32_bf16((a),(b),(c),0,0,0)

__device__ __forceinline__ short f2bf(float x) {
  unsigned u = __float_as_uint(x);
  return (short)((u + 0x7fffu + ((u >> 16) & 1u)) >> 16);
}
__device__ __forceinline__ float bf2f(short s) {
  return __uint_as_float(((unsigned)(unsigned short)s) << 16);
}

// ---------------------------------------------------------------------------
// One-shot fp32 -> split-bf16 (hi/lo) conversion of gemm0 operands.
// Row r < 4096: A = [mems;w] row; else B = Wqkv row (r-4096). One row/block.
// ---------------------------------------------------------------------------
__global__ __launch_bounds__(256)
void convert_k(const float* __restrict__ mems, const float* __restrict__ w,
               const float* __restrict__ Wqkv,
               short* __restrict__ Ah, short* __restrict__ Al,
               short* __restrict__ Bh, short* __restrict__ Bl)
{
  const int row = blockIdx.x;
  const int t = threadIdx.x;            // 256 threads x 4 elems = 1024
  const float* src;
  short *dh, *dl;
  size_t r2;
  if (row < 4096) {
    src = (row < 2048) ? (mems + (size_t)row * 1024)
                       : (w + (size_t)(row - 2048) * 1024);
    dh = Ah; dl = Al; r2 = row;
  } else {
    src = Wqkv + (size_t)(row - 4096) * 1024;
    dh = Bh; dl = Bl; r2 = row - 4096;
  }
  float4 v = *reinterpret_cast<const float4*>(src + t * 4);
  short h0 = f2bf(v.x), h1 = f2bf(v.y), h2 = f2bf(v.z), h3 = f2bf(v.w);
  s4v hi = {h0, h1, h2, h3};
  s4v lo = {f2bf(v.x - bf2f(h0)), f2bf(v.y - bf2f(h1)),
            f2bf(v.z - bf2f(h2)), f2bf(v.w - bf2f(h3))};
  *reinterpret_cast<s4v*>(dh + r2 * 1024 + t * 4) = hi;
  *reinterpret_cast<s4v*>(dl + r2 * 1024 + t * 4) = lo;
}

// ---------------------------------------------------------------------------
// split-bf16 MFMA GEMM: C[m][n] = sum_k A[m][k]*Bmat[n][k], K=1024, tile 128x128
// MODE0: A/B pre-converted bf16 hi/lo (SA*/SB*); staging via ASYNC
//        global_load_lds width=16; XOR slot swizzle carried by the per-lane
//        GLOBAL source address. Epilogue: Qw/Qr hi/lo (+bias), K hi/lo, V^T.
//        The 128 blocks of the discarded q/mems corner (n0<1024 && m0<2048)
//        run the W_r GEMM instead (fp32 inline-convert staging, RK scatter) —
//        this FUSES the old gemm1 dispatch into gemm0's otherwise-dead blocks.
// MODE2: A=(avp0+avp1)*linv_row fp32; epilogue: out fp32
// ---------------------------------------------------------------------------
template<int MODE>
__global__ __launch_bounds__(256)
void gemm_mfma(const float* __restrict__ A0, const float* __restrict__ A1,
               const float* __restrict__ Bmat,
               const short* __restrict__ SAh, const short* __restrict__ SAl,
               const short* __restrict__ SBh, const short* __restrict__ SBl,
               const float* __restrict__ Ar,  const float* __restrict__ Wrb,
               short* __restrict__ R0h, short* __restrict__ R0l,
               short* __restrict__ P0h, short* __restrict__ P0l,
               short* __restrict__ P1h, short* __restrict__ P1l,
               short* __restrict__ P2h, short* __restrict__ P2l,
               short* __restrict__ P3,
               float* __restrict__ Ofp,
               const float* __restrict__ rwb, const float* __restrict__ rrb,
               const float* __restrict__ Wl)
{
  __shared__ short Ah[128*64];
  __shared__ short Al[128*64];
  __shared__ short Bh[128*64];
  __shared__ short Bl[128*64];
  const int n0 = blockIdx.x * 128, m0 = blockIdx.y * 128;
  const bool do_rk = (MODE == 0) && (n0 < 1024) && (m0 < 2048);
  const int tid = threadIdx.x;
  const int L = tid & 63, lr = L & 15, lg = L >> 4;
  const int wid = tid >> 6, wm = wid >> 1, wn = wid & 1;
  const int srow = tid >> 1, sseg = tid & 1;

  const float* arow = nullptr;
  const float* arow2 = nullptr;
  const short* stgsrc = nullptr;
  short* stgdst = nullptr;
  int stgrow0 = 0;
  if (MODE == 0) {
    if (do_rk) {
      arow = Ar + (size_t)(m0 + srow) * 1024;        // r rows
    } else {
      if (wid == 0)      { stgsrc = SAh; stgdst = Ah; stgrow0 = m0; }
      else if (wid == 1) { stgsrc = SAl; stgdst = Al; stgrow0 = m0; }
      else if (wid == 2) { stgsrc = SBh; stgdst = Bh; stgrow0 = n0; }
      else               { stgsrc = SBl; stgdst = Bl; stgrow0 = n0; }
    }
  } else {
    arow = A0 + (size_t)(m0 + srow) * 1024;
    if (MODE == 2) arow2 = A1 + (size_t)(m0 + srow) * 1024;
  }
  const float* brow = (MODE == 0)
      ? (do_rk ? (Wrb + (size_t)(n0 + srow) * 1024) : nullptr)
      : (Bmat + (size_t)(n0 + srow) * 1024);

  const f4v fz = {0.f, 0.f, 0.f, 0.f};
  f4v acc[4][4];
#pragma unroll
  for (int a = 0; a < 4; ++a)
#pragma unroll
    for (int bq = 0; bq < 4; ++bq) acc[a][bq] = fz;

  for (int k0 = 0; k0 < 1024; k0 += 64) {
    __syncthreads();
    if (MODE == 0 && !do_rk) {
#pragma unroll
      for (int e = 0; e < 16; ++e) {
        int s2 = e * 64 + L;                     // slot within region
        int row = s2 >> 3, kg = (s2 & 7) ^ (row & 7);
        const short* src = stgsrc + (size_t)(stgrow0 + row) * 1024 + k0 + kg * 8;
        __builtin_amdgcn_global_load_lds(
            (const __attribute__((address_space(1))) void*)src,
            (__attribute__((address_space(3))) void*)(stgdst + (size_t)e * 512),
            16, 0, 0);
      }
    } else {
      float wgt = 1.0f;
      if (MODE == 2) {
        int m = m0 + srow;
        wgt = Wl[((size_t)((m & 1) * NHh) + (k0 >> 6)) * 1024 + (m >> 1)];
      }
      const float* pa = arow + k0 + sseg * 32;
#pragma unroll
      for (int v = 0; v < 4; ++v) {
        float4 f0 = *reinterpret_cast<const float4*>(pa + v * 8);
        float4 f1 = *reinterpret_cast<const float4*>(pa + v * 8 + 4);
        if (MODE == 2) {
          const float* pa2 = arow2 + k0 + sseg * 32;
          float4 g0 = *reinterpret_cast<const float4*>(pa2 + v * 8);
          float4 g1 = *reinterpret_cast<const float4*>(pa2 + v * 8 + 4);
          f0.x = (f0.x + g0.x) * wgt; f0.y = (f0.y + g0.y) * wgt;
          f0.z = (f0.z + g0.z) * wgt; f0.w = (f0.w + g0.w) * wgt;
          f1.x = (f1.x + g1.x) * wgt; f1.y = (f1.y + g1.y) * wgt;
          f1.z = (f1.z + g1.z) * wgt; f1.w = (f1.w + g1.w) * wgt;
        }
        float bf[8] = {f0.x, f0.y, f0.z, f0.w, f1.x, f1.y, f1.z, f1.w};
        s8v hi, lo;
#pragma unroll
        for (int e = 0; e < 8; ++e) {
          short h = f2bf(bf[e]); hi[e] = h; lo[e] = f2bf(bf[e] - bf2f(h));
        }
        int slot = srow * 8 + ((sseg * 4 + v) ^ (srow & 7));
        *reinterpret_cast<s8v*>(Ah + slot * 8) = hi;
        *reinterpret_cast<s8v*>(Al + slot * 8) = lo;
      }
      const float* pb = brow + k0 + sseg * 32;
#pragma unroll
      for (int v = 0; v < 4; ++v) {
        float4 f0 = *reinterpret_cast<const float4*>(pb + v * 8);
        float4 f1 = *reinterpret_cast<const float4*>(pb + v * 8 + 4);
        float bf[8] = {f0.x, f0.y, f0.z, f0.w, f1.x, f1.y, f1.z, f1.w};
        s8v hi, lo;
#pragma unroll
        for (int e = 0; e < 8; ++e) {
          short h = f2bf(bf[e]); hi[e] = h; lo[e] = f2bf(bf[e] - bf2f(h));
        }
        int slot = srow * 8 + ((sseg * 4 + v) ^ (srow & 7));
        *reinterpret_cast<s8v*>(Bh + slot * 8) = hi;
        *reinterpret_cast<s8v*>(Bl + slot * 8) = lo;
      }
    }
    __syncthreads();
#pragma unroll
    for (int ks = 0; ks < 2; ++ks) {
      s8v a_h[4], a_l[4], b_h[4], b_l[4];
#pragma unroll
      for (int x = 0; x < 4; ++x) {
        int ra = wm * 64 + x * 16 + lr;
        int sa = ra * 8 + ((ks * 4 + lg) ^ (ra & 7));
        a_h[x] = *reinterpret_cast<const s8v*>(Ah + sa * 8);
        a_l[x] = *reinterpret_cast<const s8v*>(Al + sa * 8);
        int rb = wn * 64 + x * 16 + lr;
        int sb = rb * 8 + ((ks * 4 + lg) ^ (rb & 7));
        b_h[x] = *reinterpret_cast<const s8v*>(Bh + sb * 8);
        b_l[x] = *reinterpret_cast<const s8v*>(Bl + sb * 8);
      }
#pragma unroll
      for (int mf = 0; mf < 4; ++mf)
#pragma unroll
        for (int nf = 0; nf < 4; ++nf) {
          acc[mf][nf] = MFMA16(a_l[mf], b_h[nf], acc[mf][nf]);
          acc[mf][nf] = MFMA16(a_h[mf], b_l[nf], acc[mf][nf]);
          acc[mf][nf] = MFMA16(a_h[mf], b_h[nf], acc[mf][nf]);
        }
    }
  }
  // ---- epilogue: C/D layout col=lane&15, row=(lane>>4)*4+reg (m89-verified)
  const int sec = (MODE == 0) ? (n0 >> 10) : 0;
#pragma unroll
  for (int mf = 0; mf < 4; ++mf)
#pragma unroll
    for (int nf = 0; nf < 4; ++nf) {
      const int n = n0 + wn * 64 + nf * 16 + lr;
#pragma unroll
      for (int r = 0; r < 4; ++r) {
        const int m = m0 + wm * 64 + mf * 16 + lg * 4 + r;
        float val = acc[mf][nf][r];
        if (MODE == 2) {
          Ofp[(size_t)m * 1024 + n] = val;
        } else if (do_rk) {                     // fused W_r GEMM -> RK scatter
          int nn = n >> 6, d = n & 63;
          size_t idx = (((size_t)nn * KL + m) << 6) + d;
          short h = f2bf(val);
          R0h[idx] = h; R0l[idx] = f2bf(val - bf2f(h));
        } else {
          int b = m & 1, t = m >> 1;
          if (sec == 0) {                       // q section: t >= 1024 guaranteed
            int i = t - 1024;
            int nn = n >> 6, d = n & 63;
            size_t idx = (((size_t)(b * NHh + nn) * QL + i) << 6) + d;
            float qw = val + rwb[n];
            float qr = val + rrb[n];
            short h = f2bf(qw);
            P0h[idx] = h; P0l[idx] = f2bf(qw - bf2f(h));
            h = f2bf(qr);
            P1h[idx] = h; P1l[idx] = f2bf(qr - bf2f(h));
          } else if (sec == 1) {                // K
            int c = n - 1024; int nn = c >> 6, d = c & 63;
            size_t idx = (((size_t)(b * NHh + nn) * KL + t) << 6) + d;
            short h = f2bf(val);
            P2h[idx] = h; P2l[idx] = f2bf(val - bf2f(h));
          } else {                              // V^T single bf16 [bn][d][t]
            int c = n - 2048; int nn = c >> 6, d = c & 63;
            size_t idx = ((size_t)(b * NHh + nn) * 64 + d) * KL + t;
            P3[idx] = f2bf(val);
          }
        }
      }
    }
}

// ---------------------------------------------------------------------------
// Fused attention — EXACT r14 shape (222 us proven: 1 wave / 32 q-rows, plain
// launch_bounds(64) -> VGPR~152, inline just-in-time loads, setprio, XCD
// decode, r3-refchecked rel-shift algebra). No l tracking (rescale_prob
// computes row sums itself).
// Grid 2048 flat: xcd=orig&7 -> bn, iblk (32x32 rows), ch (2 j-chunks).
// BD rel-shift: G[ir][c] = Qr_i * RK[BASE+c], BASE = 992-i0+j0; mf0 uses
// c in [16,95] (skip ci0), mf1 uses c in [0,79] (skip ci5);
// gather cl = 31 - mf*16 - ir16 + jf*16 + lr.
// ---------------------------------------------------------------------------
__global__ __launch_bounds__(64)
void attn_fused(const short* __restrict__ Qwh, const short* __restrict__ Qwl,
                const short* __restrict__ Qrh, const short* __restrict__ Qrl,
                const short* __restrict__ Kh,  const short* __restrict__ Klo,
                const short* __restrict__ RKh, const short* __restrict__ RKl,
                const short* __restrict__ Vb,
                float* __restrict__ prob,
                float* __restrict__ avp)
{
  __shared__ float Gs[96 * 20];     // [c][i16] fp32, per-mf sequential reuse
  __shared__ short Ps[32 * 72];     // P tile bf16 for PV A-frags
  const int L = threadIdx.x;
  const int lr = L & 15, lg = L >> 4;
  // XCD-locality decode (bijection over 2048 = 8 xcd x 4 bnl x 64 rest)
  const int orig = blockIdx.x;
  const int xcd  = orig & 7;
  const int k2   = orig >> 3;              // 0..255
  const int bn   = xcd * 4 + (k2 >> 6);    // 0..31
  const int rest = k2 & 63;
  const int iblk = rest >> 1, ch = rest & 1;
  const int nh = bn & 15, b = bn >> 4;
  const int i0 = iblk * 32;
  const f4v fz = {0.f, 0.f, 0.f, 0.f};

  int T = ((i0 + 1055) >> 6) + 1; if (T > 32) T = 32;
  const int t0 = (ch * T) >> 1;
  const int t1 = ((ch + 1) * T) >> 1;

  // Q A-frags for both mf halves, held for the whole kernel
  s8v qw_h[2][2], qw_l[2][2], qr_h[2][2], qr_l[2][2];
#pragma unroll
  for (int mf = 0; mf < 2; ++mf)
#pragma unroll
    for (int ks = 0; ks < 2; ++ks) {
      size_t idx = (((size_t)bn * QL + i0 + mf * 16 + lr) << 6) + ks * 32 + lg * 8;
      qw_h[mf][ks] = *reinterpret_cast<const s8v*>(Qwh + idx);
      qw_l[mf][ks] = *reinterpret_cast<const s8v*>(Qwl + idx);
      qr_h[mf][ks] = *reinterpret_cast<const s8v*>(Qrh + idx);
      qr_l[mf][ks] = *reinterpret_cast<const s8v*>(Qrl + idx);
    }

  f4v av[2][4];
#pragma unroll
  for (int mf = 0; mf < 2; ++mf)
#pragma unroll
    for (int r = 0; r < 4; ++r) av[mf][r] = fz;

  float* probb = prob + (size_t)bn * QL * KL;

  for (int jt = t0; jt < t1; ++jt) {
    const int j0 = jt * 64;
    const int BASE = 992 - i0 + j0;
    // ---- BD window GEMM (inline loads, shared across both mf)
    f4v gacc[2][5];
#pragma unroll
    for (int mf = 0; mf < 2; ++mf)
#pragma unroll
      for (int gi = 0; gi < 5; ++gi) gacc[mf][gi] = fz;
    __builtin_amdgcn_s_setprio(1);
#pragma unroll
    for (int ci = 0; ci < 6; ++ci) {
      int rg = BASE + ci * 16 + lr;
      rg = rg < 0 ? 0 : (rg > 2047 ? 2047 : rg);  // clamped rows feed masked elems only
      size_t ridx = ((size_t)nh * KL + rg) << 6;
      s8v r_h[2], r_l[2];
#pragma unroll
      for (int ks = 0; ks < 2; ++ks) {
        r_h[ks] = *reinterpret_cast<const s8v*>(RKh + ridx + ks * 32 + lg * 8);
        r_l[ks] = *reinterpret_cast<const s8v*>(RKl + ridx + ks * 32 + lg * 8);
      }
#pragma unroll
      for (int mf = 0; mf < 2; ++mf) {
        if (mf == 0 && ci == 0) continue;   // mf0 uses c in [16,95]
        if (mf == 1 && ci == 5) continue;   // mf1 uses c in [0,79]
        const int gi = (mf == 0) ? (ci - 1) : ci;
#pragma unroll
        for (int ks = 0; ks < 2; ++ks) {
          gacc[mf][gi] = MFMA16(qr_l[mf][ks], r_h[ks], gacc[mf][gi]);
          gacc[mf][gi] = MFMA16(qr_h[mf][ks], r_l[ks], gacc[mf][gi]);
          gacc[mf][gi] = MFMA16(qr_h[mf][ks], r_h[ks], gacc[mf][gi]);
        }
      }
    }
    __builtin_amdgcn_s_setprio(0);
    // ---- per mf: spill G, AC GEMM (inline K loads), gather+exp+write
#pragma unroll
    for (int mf = 0; mf < 2; ++mf) {
#pragma unroll
      for (int gi = 0; gi < 5; ++gi) {
        int c = (mf == 0 ? 16 : 0) + gi * 16 + lr;
        *reinterpret_cast<f4v*>(Gs + c * 20 + lg * 4) = gacc[mf][gi];
      }
      f4v sfr[4];
      __builtin_amdgcn_s_setprio(1);
#pragma unroll
      for (int jf = 0; jf < 4; ++jf) {
        sfr[jf] = fz;
        size_t kidx = ((size_t)bn * KL + j0 + jf * 16 + lr) << 6;
#pragma unroll
        for (int ks = 0; ks < 2; ++ks) {
          s8v k_h = *reinterpret_cast<const s8v*>(Kh  + kidx + ks * 32 + lg * 8);
          s8v k_l = *reinterpret_cast<const s8v*>(Klo + kidx + ks * 32 + lg * 8);
          sfr[jf] = MFMA16(qw_l[mf][ks], k_h, sfr[jf]);
          sfr[jf] = MFMA16(qw_h[mf][ks], k_l, sfr[jf]);
          sfr[jf] = MFMA16(qw_h[mf][ks], k_h, sfr[jf]);
        }
      }
      __builtin_amdgcn_s_setprio(0);
#pragma unroll
      for (int jf = 0; jf < 4; ++jf) {
#pragma unroll
        for (int r = 0; r < 4; ++r) {
          const int ir16 = lg * 4 + r;
          const int i = i0 + mf * 16 + ir16;
          const int j = j0 + jf * 16 + lr;
          const int cl = 31 - mf * 16 - ir16 + jf * 16 + lr;
          float s = (sfr[jf][r] + Gs[cl * 20 + ir16]) * SCALEh;
          float p = (j <= i + 1024) ? __expf(s) : 0.f;
          probb[(size_t)i * KL + j] = p;
          Ps[(mf * 16 + ir16) * 72 + jf * 16 + lr] = f2bf(p);
        }
      }
    }
    // ---- PV: inline V loads shared across both mf
    __builtin_amdgcn_s_setprio(1);
#pragma unroll
    for (int ks = 0; ks < 2; ++ks) {
      s8v pa[2];
#pragma unroll
      for (int mf = 0; mf < 2; ++mf)
        pa[mf] = *reinterpret_cast<const s8v*>(Ps + (mf * 16 + lr) * 72 + ks * 32 + lg * 8);
#pragma unroll
      for (int df = 0; df < 4; ++df) {
        s8v vfr = *reinterpret_cast<const s8v*>(
            Vb + ((size_t)bn * 64 + df * 16 + lr) * KL + j0 + ks * 32 + lg * 8);
#pragma unroll
        for (int mf = 0; mf < 2; ++mf)
          av[mf][df] = MFMA16(pa[mf], vfr, av[mf][df]);
      }
    }
    __builtin_amdgcn_s_setprio(0);
  }

  // ---- AV' partials
#pragma unroll
  for (int mf = 0; mf < 2; ++mf)
#pragma unroll
    for (int df = 0; df < 4; ++df)
#pragma unroll
      for (int r = 0; r < 4; ++r) {
        int i = i0 + mf * 16 + lg * 4 + r;
        int d = df * 16 + lr;
        avp[(size_t)ch * 2097152 + ((size_t)i * 2 + b) * 1024 + nh * 64 + d] = av[mf][df][r];
      }
}

// ---------------------------------------------------------------------------
// prob[row][j] = p'[row][j] / l_row for valid j (else exact 0), where
// l_row = sum_j p'. Computes the row sum itself, skips reading fully-masked
// chunks, writes the full row (zeros in masked region), and emits linv.
// ---------------------------------------------------------------------------
__global__ __launch_bounds__(256)
void rescale_prob(float* __restrict__ prob, float* __restrict__ linv)
{
  __shared__ float red[8];
  const int row = blockIdx.x;                 // bn*1024 + i
  const int i = row & 1023;
  const int lim = i + 1024;                   // j <= lim valid
  const int tid = threadIdx.x;
  const int jb = tid * 8;
  float* p = prob + ((size_t)row << 11) + jb;

  float4 a = {0.f, 0.f, 0.f, 0.f}, c = {0.f, 0.f, 0.f, 0.f};
  if (jb <= lim) {                            // at least one valid element
    a = *reinterpret_cast<const float4*>(p);
    c = *reinterpret_cast<const float4*>(p + 4);
    if (jb + 1 > lim) a.y = 0.f;
    if (jb + 2 > lim) a.z = 0.f;
    if (jb + 3 > lim) a.w = 0.f;
    if (jb + 4 > lim) c.x = 0.f;
    if (jb + 5 > lim) c.y = 0.f;
    if (jb + 6 > lim) c.z = 0.f;
    if (jb + 7 > lim) c.w = 0.f;
  }
  float sum = a.x + a.y + a.z + a.w + c.x + c.y + c.z + c.w;
#pragma unroll
  for (int mk = 1; mk <= 32; mk <<= 1) sum += __shfl_xor(sum, mk, 64);
  if ((tid & 63) == 0) red[tid >> 6] = sum;
  __syncthreads();
  float l = red[0] + red[1] + red[2] + red[3];
  float wgt = 1.0f / l;
  if (tid == 0) linv[row] = wgt;

  a.x *= wgt; a.y *= wgt; a.z *= wgt; a.w *= wgt;
  c.x *= wgt; c.y *= wgt; c.z *= wgt; c.w *= wgt;
  *reinterpret_cast<float4*>(p) = a;
  *reinterpret_cast<float4*>(p + 4) = c;
}

// ---------------------------------------------------------------------------
extern "C" void kernel_launch(void* const* d_in, const int* in_sizes, int n_in,
                              void* d_out, int out_size, void* d_ws, size_t ws_size,
                              hipStream_t stream)
{
  (void)in_sizes; (void)n_in; (void)out_size; (void)ws_size;
  const float* w    = (const float*)d_in[0];
  const float* r    = (const float*)d_in[1];
  const float* rwb  = (const float*)d_in[2];
  const float* rrb  = (const float*)d_in[3];
  const float* mems = (const float*)d_in[4];
  const float* Wqkv = (const float*)d_in[5];
  const float* Wr   = (const float*)d_in[6];
  const float* Wo   = (const float*)d_in[7];

  float* out  = (float*)d_out;
  float* prob = out + 2097152;

  // convert_k scratch lives in the prob region (256 MB) — written and fully
  // consumed by gemm0 BEFORE attn overwrites prob (stream-ordered).
  short* Abf_h = (short*)prob;              // 4096x1024
  short* Abf_l = Abf_h + 4194304;
  short* Bbf_h = Abf_l + 4194304;           // 3072x1024
  short* Bbf_l = Bbf_h + 3145728;

  // workspace: 67,371,008 B total (identical to the round-1/14 passing layout)
  short* Qwh = (short*)d_ws;
  short* Qwl = Qwh + 2097152;
  short* Qrh = Qwl + 2097152;
  short* Qrl = Qrh + 2097152;
  short* Kh  = Qrl + 2097152;
  short* Klo = Kh  + 4194304;
  short* Vb  = Klo + 4194304;
  short* RKh = Vb  + 4194304;
  short* RKl = RKh + 2097152;
  float* avp  = (float*)(RKl + 2097152);    // 2 x 2,097,152 floats
  float* linv = avp + 4194304;              // 32,768 floats

  convert_k<<<dim3(7168), 256, 0, stream>>>(
      mems, w, Wqkv, Abf_h, Abf_l, Bbf_h, Bbf_l);
  gemm_mfma<0><<<dim3(24, 32), 256, 0, stream>>>(
      nullptr, nullptr, nullptr, Abf_h, Abf_l, Bbf_h, Bbf_l,
      r, Wr, RKh, RKl,
      Qwh, Qwl, Qrh, Qrl, Kh, Klo, Vb, nullptr, rwb, rrb, nullptr);
  attn_fused<<<dim3(2048), 64, 0, stream>>>(
      Qwh, Qwl, Qrh, Qrl, Kh, Klo, RKh, RKl, Vb, prob, avp);
  rescale_prob<<<32768, 256, 0, stream>>>(prob, linv);
  gemm_mfma<2><<<dim3(8, 16), 256, 0, stream>>>(
      avp, avp + 2097152, Wo, nullptr, nullptr, nullptr, nullptr,
      nullptr, nullptr, nullptr, nullptr,
      nullptr, nullptr, nullptr, nullptr, nullptr, nullptr, nullptr,
      out, nullptr, nullptr, linv);
}